// Round 2
// baseline (455.982 us; speedup 1.0000x reference)
//
#include <hip/hip_runtime.h>

#define SEQ   4096
#define EMB   1280
#define NH    16
#define HD    80
#define HDP   96
#define O3    3840
#define SEGLEN 1024
#define NSEG  4
#define SCALE 8.94427190999915878564f  // sqrt(80); reference MULTIPLIES scores by sqrt(d)

typedef unsigned short u16;
typedef __attribute__((ext_vector_type(8))) _Float16 f16x8;
typedef __attribute__((ext_vector_type(4))) float    f32x4;

__device__ __forceinline__ u16 f2h(float f) {
  union { _Float16 h; u16 u; } v; v.h = (_Float16)f; return v.u;
}
__device__ __forceinline__ float h2f(u16 b) {
  union { u16 u; _Float16 h; } v; v.u = b; return (float)v.h;
}

// ---------------- fp32 -> fp16 convert (x4 vectorized) ----------------
__global__ void cvt4_kernel(const float* __restrict__ in, u16* __restrict__ out, int n4) {
  int i = blockIdx.x * blockDim.x + threadIdx.x;
  if (i >= n4) return;
  float4 f = ((const float4*)in)[i];
  union { u16 h[4]; uint2 v; } o;
  o.h[0] = f2h(f.x); o.h[1] = f2h(f.y); o.h[2] = f2h(f.z); o.h[3] = f2h(f.w);
  ((uint2*)out)[i] = o.v;
}

// ---------------- fp16 MFMA GEMM: C[M][N] = A[M][K] * W[N][K]^T + bias ----------------
template<int OUTF>
__global__ __launch_bounds__(256)
void gemm_bias_kernel(const u16* __restrict__ A, const u16* __restrict__ W,
                      const float* __restrict__ bias, void* __restrict__ Cout,
                      int N, int K) {
  __shared__ u16 As[128][40];   // +8 pad
  __shared__ u16 Bs[128][40];
  const int tid  = threadIdx.x;
  const int bm   = blockIdx.y, bn = blockIdx.x;
  const int lane = tid & 63;
  const int wid  = tid >> 6;
  const int wm   = (wid >> 1) * 64, wn = (wid & 1) * 64;
  const int lr   = lane & 15, quad = lane >> 4;

  f32x4 acc[4][4];
  const f32x4 z4 = {0.f, 0.f, 0.f, 0.f};
  #pragma unroll
  for (int i = 0; i < 4; ++i)
    #pragma unroll
    for (int j = 0; j < 4; ++j) acc[i][j] = z4;

  const int r0 = tid >> 2;          // 0..63
  const int c8 = (tid & 3) * 8;     // 0,8,16,24
  const u16* Ab = A + (size_t)(bm * 128) * K;
  const u16* Wb = W + (size_t)(bn * 128) * K;

  for (int kt = 0; kt < K; kt += 32) {
    #pragma unroll
    for (int r = 0; r < 2; ++r) {
      int row = r0 + r * 64;
      *(uint4*)&As[row][c8] = *(const uint4*)&Ab[(size_t)row * K + kt + c8];
      *(uint4*)&Bs[row][c8] = *(const uint4*)&Wb[(size_t)row * K + kt + c8];
    }
    __syncthreads();
    f16x8 aF[4], bF[4];
    #pragma unroll
    for (int i = 0; i < 4; ++i) aF[i] = *(const f16x8*)&As[wm + i * 16 + lr][quad * 8];
    #pragma unroll
    for (int j = 0; j < 4; ++j) bF[j] = *(const f16x8*)&Bs[wn + j * 16 + lr][quad * 8];
    #pragma unroll
    for (int i = 0; i < 4; ++i)
      #pragma unroll
      for (int j = 0; j < 4; ++j)
        acc[i][j] = __builtin_amdgcn_mfma_f32_16x16x32_f16(aF[i], bF[j], acc[i][j], 0, 0, 0);
    __syncthreads();
  }

  // epilogue: D row = quad*4 + r, col = lr
  #pragma unroll
  for (int i = 0; i < 4; ++i) {
    int rowb = bm * 128 + wm + i * 16 + quad * 4;
    #pragma unroll
    for (int j = 0; j < 4; ++j) {
      int col = bn * 128 + wn + j * 16 + lr;
      float bv = bias[col];
      #pragma unroll
      for (int r = 0; r < 4; ++r) {
        float v = acc[i][j][r] + bv;
        if (OUTF) ((float*)Cout)[(size_t)(rowb + r) * N + col] = v;
        else      ((u16*)Cout)[(size_t)(rowb + r) * N + col] = f2h(v);
      }
    }
  }
}

// ---------------- RoPE + layout reorg ----------------
__global__ void rope_reorg_kernel(const u16* __restrict__ qkv, const float* __restrict__ cosp,
                                  const float* __restrict__ sinp, u16* __restrict__ Qp,
                                  u16* __restrict__ Kp, u16* __restrict__ Vt) {
  int idx = blockIdx.x * blockDim.x + threadIdx.x;  // NH*SEQ*HDP total
  int d = idx % HDP;
  int s = (idx / HDP) % SEQ;
  int h = idx / (HDP * SEQ);
  size_t po = ((size_t)h * SEQ + s) * HDP + d;
  if (d >= HD) { Qp[po] = 0; Kp[po] = 0; return; }
  const size_t rowb = (size_t)s * O3;
  float q = h2f(qkv[rowb + h * HD + d]);
  float k = h2f(qkv[rowb + EMB + h * HD + d]);
  u16   v = qkv[rowb + 2 * EMB + h * HD + d];
  float c  = cosp[s * HD + d];
  float sn = sinp[s * HD + d];
  int   dp = (d < 40) ? d + 40 : d - 40;
  float qp_ = h2f(qkv[rowb + h * HD + dp]);
  float kp_ = h2f(qkv[rowb + EMB + h * HD + dp]);
  float qo = (d < 40) ? (q * c - qp_ * sn) : (q * c + qp_ * sn);
  float ko = (d < 40) ? (k * c - kp_ * sn) : (k * c + kp_ * sn);
  Qp[po] = f2h(qo * SCALE);
  Kp[po] = f2h(ko);
  Vt[((size_t)(h * HD + d)) * SEQ + s] = v;
}

// ---------------- attention: one block per (seg, head, 16-row q-block) ----------------
__global__ __launch_bounds__(256)
void attn_kernel(const u16* __restrict__ Qp, const u16* __restrict__ Kp,
                 const u16* __restrict__ Vt, u16* __restrict__ attnO) {
  __shared__ float sc[16][1028];   // fp32 scores, +4 pad
  __shared__ u16   Pb[16][1032];   // fp16 probs, +8 pad
  __shared__ u16   Qs[16][HDP];
  __shared__ float prt[4][16][84]; // per-wave PV partials, +4 pad

  const int tid = threadIdx.x;
  const int lane = tid & 63, w = tid >> 6;
  const int lr = lane & 15, quad = lane >> 4;
  const int qb = blockIdx.x, h = blockIdx.y, sg = blockIdx.z;
  const int seg0 = sg * SEGLEN;
  const int q0 = seg0 + qb * 16;

  for (int i = tid; i < 16 * HDP; i += 256) {
    int r = i / HDP, d = i % HDP;
    Qs[r][d] = Qp[((size_t)h * SEQ + q0 + r) * HDP + d];
  }
  __syncthreads();

  // phase 1: S = Q K^T
  f16x8 aF[3];
  #pragma unroll
  for (int ks = 0; ks < 3; ++ks) aF[ks] = *(const f16x8*)&Qs[lr][ks * 32 + quad * 8];
  const u16* Kbase = Kp + (size_t)h * SEQ * HDP;
  for (int t = 0; t < 16; ++t) {
    int col0 = w * 256 + t * 16;
    f32x4 d = {0.f, 0.f, 0.f, 0.f};
    const u16* Krow = Kbase + (size_t)(seg0 + col0 + lr) * HDP;
    #pragma unroll
    for (int ks = 0; ks < 3; ++ks) {
      f16x8 bF = *(const f16x8*)&Krow[ks * 32 + quad * 8];
      d = __builtin_amdgcn_mfma_f32_16x16x32_f16(aF[ks], bF, d, 0, 0, 0);
    }
    #pragma unroll
    for (int r = 0; r < 4; ++r) sc[quad * 4 + r][col0 + lr] = d[r];
  }
  __syncthreads();

  // phase 2: softmax, wave w owns rows 4w..4w+3
  for (int rr = w * 4; rr < w * 4 + 4; ++rr) {
    float x[16];
    float m = -3.4e38f;
    #pragma unroll
    for (int i = 0; i < 16; ++i) { x[i] = sc[rr][lane + i * 64]; m = fmaxf(m, x[i]); }
    #pragma unroll
    for (int o = 32; o > 0; o >>= 1) m = fmaxf(m, __shfl_xor(m, o, 64));
    float s = 0.f;
    #pragma unroll
    for (int i = 0; i < 16; ++i) { x[i] = __expf(x[i] - m); s += x[i]; }
    #pragma unroll
    for (int o = 32; o > 0; o >>= 1) s += __shfl_xor(s, o, 64);
    float inv = 1.0f / s;
    #pragma unroll
    for (int i = 0; i < 16; ++i) Pb[rr][lane + i * 64] = f2h(x[i] * inv);
  }
  __syncthreads();

  // phase 3: O = P V, split K across waves + LDS reduce
  f32x4 acc[5];
  const f32x4 z4 = {0.f, 0.f, 0.f, 0.f};
  #pragma unroll
  for (int n = 0; n < 5; ++n) acc[n] = z4;
  for (int ks = 0; ks < 8; ++ks) {
    int kk = w * 256 + ks * 32;
    f16x8 aP = *(const f16x8*)&Pb[lr][kk + quad * 8];
    #pragma unroll
    for (int n = 0; n < 5; ++n) {
      const u16* Vrow = Vt + ((size_t)(h * HD + n * 16 + lr)) * SEQ + seg0 + kk + quad * 8;
      f16x8 bF = *(const f16x8*)Vrow;
      acc[n] = __builtin_amdgcn_mfma_f32_16x16x32_f16(aP, bF, acc[n], 0, 0, 0);
    }
  }
  #pragma unroll
  for (int n = 0; n < 5; ++n)
    #pragma unroll
    for (int r = 0; r < 4; ++r)
      prt[w][quad * 4 + r][n * 16 + lr] = acc[n][r];
  __syncthreads();
  for (int i = tid; i < 16 * HD; i += 256) {
    int r = i / HD, d = i % HD;
    float sum = prt[0][r][d] + prt[1][r][d] + prt[2][r][d] + prt[3][r][d];
    attnO[((size_t)(q0 + r)) * EMB + h * HD + d] = f2h(sum);
  }
}

extern "C" void kernel_launch(void* const* d_in, const int* in_sizes, int n_in,
                              void* d_out, int out_size, void* d_ws, size_t ws_size,
                              hipStream_t stream) {
  const float* hs     = (const float*)d_in[0];
  const float* w_qkv  = (const float*)d_in[1];
  const float* b_qkv  = (const float*)d_in[2];
  const float* w_proj = (const float*)d_in[3];
  const float* b_proj = (const float*)d_in[4];
  const float* cosp   = (const float*)d_in[5];
  const float* sinp   = (const float*)d_in[6];
  float* out = (float*)d_out;

  char* p = (char*)d_ws;
  auto take = [&](size_t bytes) { char* q = p; p += (bytes + 255) & ~(size_t)255; return q; };
  u16* hsH    = (u16*)take((size_t)SEQ * EMB * 2);
  u16* wqkvH  = (u16*)take((size_t)O3 * EMB * 2);
  u16* wprojH = (u16*)take((size_t)EMB * EMB * 2);
  u16* qkvO   = (u16*)take((size_t)SEQ * O3 * 2);
  u16* Qp     = (u16*)take((size_t)NH * SEQ * HDP * 2);
  u16* Kp     = (u16*)take((size_t)NH * SEQ * HDP * 2);
  u16* Vt     = (u16*)take((size_t)NH * HD * SEQ * 2);
  u16* attnH  = (u16*)take((size_t)SEQ * EMB * 2);

  int n1 = SEQ * EMB / 4, n2 = O3 * EMB / 4, n3 = EMB * EMB / 4;
  cvt4_kernel<<<(n1 + 255) / 256, 256, 0, stream>>>(hs, hsH, n1);
  cvt4_kernel<<<(n2 + 255) / 256, 256, 0, stream>>>(w_qkv, wqkvH, n2);
  cvt4_kernel<<<(n3 + 255) / 256, 256, 0, stream>>>(w_proj, wprojH, n3);

  gemm_bias_kernel<0><<<dim3(O3 / 128, SEQ / 128), 256, 0, stream>>>(hsH, wqkvH, b_qkv, qkvO, O3, EMB);

  rope_reorg_kernel<<<(NH * SEQ * HDP) / 256, 256, 0, stream>>>(qkvO, cosp, sinp, Qp, Kp, Vt);

  attn_kernel<<<dim3(SEGLEN / 16, NH, NSEG), 256, 0, stream>>>(Qp, Kp, Vt, attnH);

  gemm_bias_kernel<1><<<dim3(EMB / 128, SEQ / 128), 256, 0, stream>>>(attnH, wprojH, b_proj, out, EMB, EMB);
}

// Round 3
// 327.786 us; speedup vs baseline: 1.3911x; 1.3911x over previous
//
#include <hip/hip_runtime.h>

#define SEQ   4096
#define EMB   1280
#define NH    16
#define HD    80
#define HDP   96
#define O3    3840
#define SEGLEN 1024
#define NSEG  4
#define SCALE 8.94427190999915878564f  // sqrt(80); reference MULTIPLIES scores by sqrt(d)

typedef unsigned short u16;
typedef __attribute__((ext_vector_type(8))) _Float16 f16x8;
typedef __attribute__((ext_vector_type(4))) float    f32x4;

__device__ __forceinline__ u16 f2h(float f) {
  union { _Float16 h; u16 u; } v; v.h = (_Float16)f; return v.u;
}
__device__ __forceinline__ float h2f(u16 b) {
  union { u16 u; _Float16 h; } v; v.u = b; return (float)v.h;
}
__device__ __forceinline__ f32x4 exp4(f32x4 x) {
  f32x4 r; r.x = __expf(x.x); r.y = __expf(x.y); r.z = __expf(x.z); r.w = __expf(x.w); return r;
}
// async global->LDS, 16B per lane. LDS dest must be wave-uniform base + lane*16.
__device__ __forceinline__ void gl2lds16(const u16* g, u16* l) {
  __builtin_amdgcn_global_load_lds(
      (const __attribute__((address_space(1))) unsigned int*)g,
      (__attribute__((address_space(3))) unsigned int*)l, 16, 0, 0);
}

// ---------------- fp32 -> fp16 convert (x4 vectorized) ----------------
__global__ void cvt4_kernel(const float* __restrict__ in, u16* __restrict__ out, int n4) {
  int i = blockIdx.x * blockDim.x + threadIdx.x;
  if (i >= n4) return;
  float4 f = ((const float4*)in)[i];
  union { u16 h[4]; uint2 v; } o;
  o.h[0] = f2h(f.x); o.h[1] = f2h(f.y); o.h[2] = f2h(f.z); o.h[3] = f2h(f.w);
  ((uint2*)out)[i] = o.v;
}

// ---------------- fp16 MFMA GEMM: C[M][N] = A[M][K] * W[N][K]^T + bias ----------------
// m97 pattern: global_load_lds width=16, unpadded [128][32] LDS (lane-contiguous dest).
template<int OUTF>
__global__ __launch_bounds__(256)
void gemm_bias_kernel(const u16* __restrict__ A, const u16* __restrict__ W,
                      const float* __restrict__ bias, void* __restrict__ Cout,
                      int N, int K) {
  __shared__ u16 As[128][32];
  __shared__ u16 Bs[128][32];
  const int tid  = threadIdx.x;
  const int bm   = blockIdx.y, bn = blockIdx.x;
  const int lane = tid & 63;
  const int wid  = tid >> 6;
  const int wm   = (wid >> 1) * 64, wn = (wid & 1) * 64;
  const int lr   = lane & 15, quad = lane >> 4;

  f32x4 acc[4][4];
  const f32x4 z4 = {0.f, 0.f, 0.f, 0.f};
  #pragma unroll
  for (int i = 0; i < 4; ++i)
    #pragma unroll
    for (int j = 0; j < 4; ++j) acc[i][j] = z4;

  const int grow = tid >> 2;        // 0..63
  const int gcol = (tid & 3) * 8;   // 0,8,16,24
  const u16* Ab = A + (size_t)(bm * 128) * K;
  const u16* Wb = W + (size_t)(bn * 128) * K;
  u16* AsL = &As[0][0] + tid * 8;   // = tid*16 bytes: row tid>>2, col (tid&3)*8
  u16* BsL = &Bs[0][0] + tid * 8;

  for (int kt = 0; kt < K; kt += 32) {
    gl2lds16(&Ab[(size_t)grow * K + kt + gcol],        AsL);
    gl2lds16(&Ab[(size_t)(grow + 64) * K + kt + gcol], AsL + 64 * 32);
    gl2lds16(&Wb[(size_t)grow * K + kt + gcol],        BsL);
    gl2lds16(&Wb[(size_t)(grow + 64) * K + kt + gcol], BsL + 64 * 32);
    __syncthreads();
    f16x8 aF[4], bF[4];
    #pragma unroll
    for (int i = 0; i < 4; ++i) aF[i] = *(const f16x8*)&As[wm + i * 16 + lr][quad * 8];
    #pragma unroll
    for (int j = 0; j < 4; ++j) bF[j] = *(const f16x8*)&Bs[wn + j * 16 + lr][quad * 8];
    #pragma unroll
    for (int i = 0; i < 4; ++i)
      #pragma unroll
      for (int j = 0; j < 4; ++j)
        acc[i][j] = __builtin_amdgcn_mfma_f32_16x16x32_f16(aF[i], bF[j], acc[i][j], 0, 0, 0);
    __syncthreads();
  }

  // epilogue: D row = quad*4 + r, col = lr
  #pragma unroll
  for (int i = 0; i < 4; ++i) {
    int rowb = bm * 128 + wm + i * 16 + quad * 4;
    #pragma unroll
    for (int j = 0; j < 4; ++j) {
      int col = bn * 128 + wn + j * 16 + lr;
      float bv = bias[col];
      #pragma unroll
      for (int r = 0; r < 4; ++r) {
        float v = acc[i][j][r] + bv;
        if (OUTF) ((float*)Cout)[(size_t)(rowb + r) * N + col] = v;
        else      ((u16*)Cout)[(size_t)(rowb + r) * N + col] = f2h(v);
      }
    }
  }
}

// ---------------- RoPE + layout reorg ----------------
// qkv[s][3840] -> Qp[h][s][96] (roped, *SCALE, zero-padded), Kp[h][s][96] (roped), Vt[h][d][s]
__global__ void rope_reorg_kernel(const u16* __restrict__ qkv, const float* __restrict__ cosp,
                                  const float* __restrict__ sinp, u16* __restrict__ Qp,
                                  u16* __restrict__ Kp, u16* __restrict__ Vt) {
  int idx = blockIdx.x * blockDim.x + threadIdx.x;  // NH*SEQ*HDP total
  int d = idx % HDP;
  int s = (idx / HDP) % SEQ;
  int h = idx / (HDP * SEQ);
  size_t po = ((size_t)h * SEQ + s) * HDP + d;
  if (d >= HD) { Qp[po] = 0; Kp[po] = 0; return; }
  const size_t rowb = (size_t)s * O3;
  float q = h2f(qkv[rowb + h * HD + d]);
  float k = h2f(qkv[rowb + EMB + h * HD + d]);
  u16   v = qkv[rowb + 2 * EMB + h * HD + d];
  float c  = cosp[s * HD + d];
  float sn = sinp[s * HD + d];
  int   dp = (d < 40) ? d + 40 : d - 40;
  float qp_ = h2f(qkv[rowb + h * HD + dp]);
  float kp_ = h2f(qkv[rowb + EMB + h * HD + dp]);
  float qo = (d < 40) ? (q * c - qp_ * sn) : (q * c + qp_ * sn);
  float ko = (d < 40) ? (k * c - kp_ * sn) : (k * c + kp_ * sn);
  Qp[po] = f2h(qo * SCALE);
  Kp[po] = f2h(ko);
  Vt[((size_t)(h * HD + d)) * SEQ + s] = v;
}

// ---------------- flash attention: block = 128 q-rows x (head, seg) ----------------
// 4 waves, each owns 32 q-rows. Loop K/V chunks of 64 cols with online softmax.
__global__ __launch_bounds__(256)
void attn_kernel(const u16* __restrict__ Qp, const u16* __restrict__ Kp,
                 const u16* __restrict__ Vt, u16* __restrict__ attnO) {
  __shared__ u16 K_l[64][104];     // 64 k-rows x 96 dims (+8 pad) = 13.0 KB
  __shared__ u16 V_l[80][72];      // 80 dims x 64 k-cols (+8 pad) = 11.3 KB
  __shared__ u16 P_l[4][32][72];   // per-wave P (32 q x 64 k, +8)  = 18.0 KB

  const int tid = threadIdx.x;
  const int lane = tid & 63, w = tid >> 6;
  const int lr = lane & 15, quad = lane >> 4;
  const int h = blockIdx.y, sg = blockIdx.z;
  const int seg0 = sg * SEGLEN;
  const int q0b = seg0 + blockIdx.x * 128;

  // Q fragments (A operand: m=lr -> q-row, k=quad*8+j), rows w*32+rt*16+lr
  f16x8 qF[2][3];
  #pragma unroll
  for (int rt = 0; rt < 2; ++rt) {
    int qrow = q0b + w * 32 + rt * 16 + lr;
    #pragma unroll
    for (int kc = 0; kc < 3; ++kc)
      qF[rt][kc] = *(const f16x8*)&Qp[((size_t)h * SEQ + qrow) * HDP + kc * 32 + quad * 8];
  }

  const u16* Kbase = Kp + (size_t)h * SEQ * HDP;
  const u16* Vbase = Vt + (size_t)h * HD * SEQ;

  const f32x4 z4 = {0.f, 0.f, 0.f, 0.f};
  f32x4 mrow[2], lrow[2], Oacc[2][5];
  #pragma unroll
  for (int rt = 0; rt < 2; ++rt) {
    mrow[rt] = (f32x4){-3.0e38f, -3.0e38f, -3.0e38f, -3.0e38f};
    lrow[rt] = z4;
    #pragma unroll
    for (int n = 0; n < 5; ++n) Oacc[rt][n] = z4;
  }

  for (int kt = 0; kt < SEGLEN; kt += 64) {
    // stage K chunk (64 x 96) and V chunk (80 x 64)
    for (int t = tid; t < 64 * 12; t += 256) {
      int r = t / 12, c = t % 12;
      *(uint4*)&K_l[r][c * 8] = *(const uint4*)&Kbase[(size_t)(seg0 + kt + r) * HDP + c * 8];
    }
    for (int t = tid; t < 80 * 8; t += 256) {
      int r = t / 8, c = t % 8;
      *(uint4*)&V_l[r][c * 8] = *(const uint4*)&Vbase[(size_t)r * SEQ + seg0 + kt + c * 8];
    }
    __syncthreads();

    // S = Q K^T for this wave's 32 rows x 64 cols, online softmax, P -> LDS
    #pragma unroll
    for (int rt = 0; rt < 2; ++rt) {
      f32x4 S[4];
      #pragma unroll
      for (int ct = 0; ct < 4; ++ct) {
        S[ct] = z4;
        #pragma unroll
        for (int kc = 0; kc < 3; ++kc) {
          f16x8 kF = *(const f16x8*)&K_l[ct * 16 + lr][kc * 32 + quad * 8];
          S[ct] = __builtin_amdgcn_mfma_f32_16x16x32_f16(qF[rt][kc], kF, S[ct], 0, 0, 0);
        }
      }
      // row max across 4 col-tiles then across lr (16 lanes)
      f32x4 mx = S[0];
      #pragma unroll
      for (int ct = 1; ct < 4; ++ct) {
        mx.x = fmaxf(mx.x, S[ct].x); mx.y = fmaxf(mx.y, S[ct].y);
        mx.z = fmaxf(mx.z, S[ct].z); mx.w = fmaxf(mx.w, S[ct].w);
      }
      #pragma unroll
      for (int off = 1; off < 16; off <<= 1) {
        mx.x = fmaxf(mx.x, __shfl_xor(mx.x, off, 64));
        mx.y = fmaxf(mx.y, __shfl_xor(mx.y, off, 64));
        mx.z = fmaxf(mx.z, __shfl_xor(mx.z, off, 64));
        mx.w = fmaxf(mx.w, __shfl_xor(mx.w, off, 64));
      }
      f32x4 mnew;
      mnew.x = fmaxf(mrow[rt].x, mx.x); mnew.y = fmaxf(mrow[rt].y, mx.y);
      mnew.z = fmaxf(mrow[rt].z, mx.z); mnew.w = fmaxf(mrow[rt].w, mx.w);
      f32x4 alpha = exp4(mrow[rt] - mnew);
      mrow[rt] = mnew;
      f32x4 rs = z4;
      #pragma unroll
      for (int ct = 0; ct < 4; ++ct) {
        S[ct] = exp4(S[ct] - mnew);
        rs += S[ct];
      }
      #pragma unroll
      for (int off = 1; off < 16; off <<= 1) {
        rs.x += __shfl_xor(rs.x, off, 64);
        rs.y += __shfl_xor(rs.y, off, 64);
        rs.z += __shfl_xor(rs.z, off, 64);
        rs.w += __shfl_xor(rs.w, off, 64);
      }
      lrow[rt] = lrow[rt] * alpha + rs;
      #pragma unroll
      for (int n = 0; n < 5; ++n) Oacc[rt][n] *= alpha;
      // P to LDS (C layout: row=quad*4+r, col=ct*16+lr)
      #pragma unroll
      for (int ct = 0; ct < 4; ++ct) {
        P_l[w][rt * 16 + quad * 4 + 0][ct * 16 + lr] = f2h(S[ct].x);
        P_l[w][rt * 16 + quad * 4 + 1][ct * 16 + lr] = f2h(S[ct].y);
        P_l[w][rt * 16 + quad * 4 + 2][ct * 16 + lr] = f2h(S[ct].z);
        P_l[w][rt * 16 + quad * 4 + 3][ct * 16 + lr] = f2h(S[ct].w);
      }
    }

    // PV: O += P V   (P wave-private in LDS; no barrier needed, lgkm dep handled)
    #pragma unroll
    for (int rt = 0; rt < 2; ++rt)
      #pragma unroll
      for (int kc2 = 0; kc2 < 2; ++kc2) {
        f16x8 pF = *(const f16x8*)&P_l[w][rt * 16 + lr][kc2 * 32 + quad * 8];
        #pragma unroll
        for (int n = 0; n < 5; ++n) {
          f16x8 vF = *(const f16x8*)&V_l[n * 16 + lr][kc2 * 32 + quad * 8];
          Oacc[rt][n] = __builtin_amdgcn_mfma_f32_16x16x32_f16(pF, vF, Oacc[rt][n], 0, 0, 0);
        }
      }
    __syncthreads();
  }

  // epilogue: normalize by 1/l, store fp16
  #pragma unroll
  for (int rt = 0; rt < 2; ++rt) {
    f32x4 inv;
    inv.x = 1.0f / lrow[rt].x; inv.y = 1.0f / lrow[rt].y;
    inv.z = 1.0f / lrow[rt].z; inv.w = 1.0f / lrow[rt].w;
    #pragma unroll
    for (int n = 0; n < 5; ++n) {
      int rowb = q0b + w * 32 + rt * 16 + quad * 4;
      int col = h * HD + n * 16 + lr;
      attnO[(size_t)(rowb + 0) * EMB + col] = f2h(Oacc[rt][n].x * inv.x);
      attnO[(size_t)(rowb + 1) * EMB + col] = f2h(Oacc[rt][n].y * inv.y);
      attnO[(size_t)(rowb + 2) * EMB + col] = f2h(Oacc[rt][n].z * inv.z);
      attnO[(size_t)(rowb + 3) * EMB + col] = f2h(Oacc[rt][n].w * inv.w);
    }
  }
}

extern "C" void kernel_launch(void* const* d_in, const int* in_sizes, int n_in,
                              void* d_out, int out_size, void* d_ws, size_t ws_size,
                              hipStream_t stream) {
  const float* hs     = (const float*)d_in[0];
  const float* w_qkv  = (const float*)d_in[1];
  const float* b_qkv  = (const float*)d_in[2];
  const float* w_proj = (const float*)d_in[3];
  const float* b_proj = (const float*)d_in[4];
  const float* cosp   = (const float*)d_in[5];
  const float* sinp   = (const float*)d_in[6];
  float* out = (float*)d_out;

  char* p = (char*)d_ws;
  auto take = [&](size_t bytes) { char* q = p; p += (bytes + 255) & ~(size_t)255; return q; };
  u16* hsH    = (u16*)take((size_t)SEQ * EMB * 2);
  u16* wqkvH  = (u16*)take((size_t)O3 * EMB * 2);
  u16* wprojH = (u16*)take((size_t)EMB * EMB * 2);
  u16* qkvO   = (u16*)take((size_t)SEQ * O3 * 2);
  u16* Qp     = (u16*)take((size_t)NH * SEQ * HDP * 2);
  u16* Kp     = (u16*)take((size_t)NH * SEQ * HDP * 2);
  u16* Vt     = (u16*)take((size_t)NH * HD * SEQ * 2);
  u16* attnH  = (u16*)take((size_t)SEQ * EMB * 2);

  int n1 = SEQ * EMB / 4, n2 = O3 * EMB / 4, n3 = EMB * EMB / 4;
  cvt4_kernel<<<(n1 + 255) / 256, 256, 0, stream>>>(hs, hsH, n1);
  cvt4_kernel<<<(n2 + 255) / 256, 256, 0, stream>>>(w_qkv, wqkvH, n2);
  cvt4_kernel<<<(n3 + 255) / 256, 256, 0, stream>>>(w_proj, wprojH, n3);

  gemm_bias_kernel<0><<<dim3(O3 / 128, SEQ / 128), 256, 0, stream>>>(hsH, wqkvH, b_qkv, qkvO, O3, EMB);

  rope_reorg_kernel<<<(NH * SEQ * HDP) / 256, 256, 0, stream>>>(qkvO, cosp, sinp, Qp, Kp, Vt);

  attn_kernel<<<dim3(SEGLEN / 128, NH, NSEG), 256, 0, stream>>>(Qp, Kp, Vt, attnH);

  gemm_bias_kernel<1><<<dim3(EMB / 128, SEQ / 128), 256, 0, stream>>>(attnH, wprojH, b_proj, out, EMB, EMB);
}

// Round 4
// 313.860 us; speedup vs baseline: 1.4528x; 1.0444x over previous
//
#include <hip/hip_runtime.h>

#define SEQ   4096
#define EMB   1280
#define NH    16
#define HD    80
#define HDP   96
#define O3    3840
#define SEGLEN 1024
#define NSEG  4
#define SCALE 8.94427190999915878564f  // sqrt(80); reference MULTIPLIES scores by sqrt(d)

typedef unsigned short u16;
typedef __attribute__((ext_vector_type(8))) _Float16 f16x8;
typedef __attribute__((ext_vector_type(4))) float    f32x4;

__device__ __forceinline__ u16 f2h(float f) {
  union { _Float16 h; u16 u; } v; v.h = (_Float16)f; return v.u;
}
__device__ __forceinline__ float h2f(u16 b) {
  union { u16 u; _Float16 h; } v; v.u = b; return (float)v.h;
}
__device__ __forceinline__ f32x4 exp4(f32x4 x) {
  f32x4 r; r.x = __expf(x.x); r.y = __expf(x.y); r.z = __expf(x.z); r.w = __expf(x.w); return r;
}
// async global->LDS, 16B per lane. LDS dest must be wave-uniform base + lane*16.
__device__ __forceinline__ void gl2lds16(const u16* g, u16* l) {
  __builtin_amdgcn_global_load_lds(
      (const __attribute__((address_space(1))) unsigned int*)g,
      (__attribute__((address_space(3))) unsigned int*)l, 16, 0, 0);
}

// ---------------- fp32 -> fp16 convert (x4 vectorized) ----------------
__global__ void cvt4_kernel(const float* __restrict__ in, u16* __restrict__ out, int n4) {
  int i = blockIdx.x * blockDim.x + threadIdx.x;
  if (i >= n4) return;
  float4 f = ((const float4*)in)[i];
  union { u16 h[4]; uint2 v; } o;
  o.h[0] = f2h(f.x); o.h[1] = f2h(f.y); o.h[2] = f2h(f.z); o.h[3] = f2h(f.w);
  ((uint2*)out)[i] = o.v;
}

// ---------------- fp16 MFMA GEMM: C[M][N] = A[M][K] * W[N][K]^T + bias ----------------
// m97 pattern: global_load_lds width=16, unpadded [128][32] LDS (lane-contiguous dest).
template<int OUTF>
__global__ __launch_bounds__(256)
void gemm_bias_kernel(const u16* __restrict__ A, const u16* __restrict__ W,
                      const float* __restrict__ bias, void* __restrict__ Cout,
                      int N, int K) {
  __shared__ u16 As[128][32];
  __shared__ u16 Bs[128][32];
  const int tid  = threadIdx.x;
  const int bm   = blockIdx.y, bn = blockIdx.x;
  const int lane = tid & 63;
  const int wid  = tid >> 6;
  const int wm   = (wid >> 1) * 64, wn = (wid & 1) * 64;
  const int lr   = lane & 15, quad = lane >> 4;

  f32x4 acc[4][4];
  const f32x4 z4 = {0.f, 0.f, 0.f, 0.f};
  #pragma unroll
  for (int i = 0; i < 4; ++i)
    #pragma unroll
    for (int j = 0; j < 4; ++j) acc[i][j] = z4;

  const int grow = tid >> 2;        // 0..63
  const int gcol = (tid & 3) * 8;   // 0,8,16,24
  const u16* Ab = A + (size_t)(bm * 128) * K;
  const u16* Wb = W + (size_t)(bn * 128) * K;
  u16* AsL = &As[0][0] + tid * 8;   // = tid*16 bytes: row tid>>2, col (tid&3)*8
  u16* BsL = &Bs[0][0] + tid * 8;

  for (int kt = 0; kt < K; kt += 32) {
    gl2lds16(&Ab[(size_t)grow * K + kt + gcol],        AsL);
    gl2lds16(&Ab[(size_t)(grow + 64) * K + kt + gcol], AsL + 64 * 32);
    gl2lds16(&Wb[(size_t)grow * K + kt + gcol],        BsL);
    gl2lds16(&Wb[(size_t)(grow + 64) * K + kt + gcol], BsL + 64 * 32);
    __syncthreads();
    f16x8 aF[4], bF[4];
    #pragma unroll
    for (int i = 0; i < 4; ++i) aF[i] = *(const f16x8*)&As[wm + i * 16 + lr][quad * 8];
    #pragma unroll
    for (int j = 0; j < 4; ++j) bF[j] = *(const f16x8*)&Bs[wn + j * 16 + lr][quad * 8];
    #pragma unroll
    for (int i = 0; i < 4; ++i)
      #pragma unroll
      for (int j = 0; j < 4; ++j)
        acc[i][j] = __builtin_amdgcn_mfma_f32_16x16x32_f16(aF[i], bF[j], acc[i][j], 0, 0, 0);
    __syncthreads();
  }

  // epilogue: D row = quad*4 + r, col = lr
  #pragma unroll
  for (int i = 0; i < 4; ++i) {
    int rowb = bm * 128 + wm + i * 16 + quad * 4;
    #pragma unroll
    for (int j = 0; j < 4; ++j) {
      int col = bn * 128 + wn + j * 16 + lr;
      float bv = bias[col];
      #pragma unroll
      for (int r = 0; r < 4; ++r) {
        float v = acc[i][j][r] + bv;
        if (OUTF) ((float*)Cout)[(size_t)(rowb + r) * N + col] = v;
        else      ((u16*)Cout)[(size_t)(rowb + r) * N + col] = f2h(v);
      }
    }
  }
}

// ---------------- RoPE + layout reorg (coalesced Vt via LDS transpose) ----------------
// block = (64 s-rows, 1 head). qkv[s][3840] -> Qp[h][s][96] (*SCALE), Kp[h][s][96], Vt[h][d][s]
__global__ __launch_bounds__(256)
void rope_reorg_kernel(const u16* __restrict__ qkv, const float* __restrict__ cosp,
                       const float* __restrict__ sinp, u16* __restrict__ Qp,
                       u16* __restrict__ Kp, u16* __restrict__ Vt) {
  __shared__ u16 Vs[64][90];   // 64 s x 80 d, stride 90 (odd word pairs -> conflict-free transpose reads)
  const int tid = threadIdx.x;
  const int s0 = blockIdx.x * 64;
  const int h  = blockIdx.y;

  // phase A: Q/K rope, coalesced read+write (d innermost)
  for (int i = tid; i < 64 * HDP; i += 256) {
    int r = i / HDP, d = i % HDP;
    int s = s0 + r;
    size_t po = ((size_t)h * SEQ + s) * HDP + d;
    if (d >= HD) { Qp[po] = 0; Kp[po] = 0; continue; }
    const size_t rowb = (size_t)s * O3;
    float q = h2f(qkv[rowb + h * HD + d]);
    float k = h2f(qkv[rowb + EMB + h * HD + d]);
    float c  = cosp[s * HD + d];
    float sn = sinp[s * HD + d];
    int   dp = (d < 40) ? d + 40 : d - 40;
    float qp_ = h2f(qkv[rowb + h * HD + dp]);
    float kp_ = h2f(qkv[rowb + EMB + h * HD + dp]);
    float qo = (d < 40) ? (q * c - qp_ * sn) : (q * c + qp_ * sn);
    float ko = (d < 40) ? (k * c - kp_ * sn) : (k * c + kp_ * sn);
    Qp[po] = f2h(qo * SCALE);
    Kp[po] = f2h(ko);
  }

  // phase B: V transpose through LDS
  for (int i = tid; i < 64 * HD; i += 256) {
    int r = i / HD, c = i % HD;
    Vs[r][c] = qkv[(size_t)(s0 + r) * O3 + 2 * EMB + h * HD + c];
  }
  __syncthreads();
  for (int i = tid; i < HD * 64; i += 256) {
    int d = i / 64, s = i % 64;
    Vt[((size_t)(h * HD + d)) * SEQ + s0 + s] = Vs[s][d];
  }
}

// ---------------- flash attention: block = 64 q-rows x (head, seg), 4 waves x 16 q ----------------
__global__ __launch_bounds__(256)
void attn_kernel(const u16* __restrict__ Qp, const u16* __restrict__ Kp,
                 const u16* __restrict__ Vt, u16* __restrict__ attnO) {
  __shared__ u16 K_l[64][104];     // 64 k-rows x 96 dims (+8 pad) = 13.3 KB
  __shared__ u16 V_l[80][72];      // 80 dims x 64 k-cols (+8 pad) = 11.5 KB
  __shared__ u16 P_l[4][16][72];   // per-wave P (16 q x 64 k, +8)  =  9.2 KB   -> 34 KB total

  const int tid = threadIdx.x;
  const int lane = tid & 63, w = tid >> 6;
  const int lr = lane & 15, quad = lane >> 4;
  const int h = blockIdx.y, sg = blockIdx.z;
  const int seg0 = sg * SEGLEN;
  const int q0b = seg0 + blockIdx.x * 64;

  // Q fragments (A operand: m=lr -> q-row, k=quad*8+j); wave rows q0b + w*16 + lr
  f16x8 qF[3];
  {
    int qrow = q0b + w * 16 + lr;
    #pragma unroll
    for (int kc = 0; kc < 3; ++kc)
      qF[kc] = *(const f16x8*)&Qp[((size_t)h * SEQ + qrow) * HDP + kc * 32 + quad * 8];
  }

  const u16* Kbase = Kp + (size_t)h * SEQ * HDP;
  const u16* Vbase = Vt + (size_t)h * HD * SEQ;

  const f32x4 z4 = {0.f, 0.f, 0.f, 0.f};
  f32x4 mrow = {-3.0e38f, -3.0e38f, -3.0e38f, -3.0e38f};
  f32x4 lrow = z4;
  f32x4 Oacc[5];
  #pragma unroll
  for (int n = 0; n < 5; ++n) Oacc[n] = z4;

  for (int kt = 0; kt < SEGLEN; kt += 64) {
    // stage K chunk (64 x 96) and V chunk (80 x 64)
    for (int t = tid; t < 64 * 12; t += 256) {
      int r = t / 12, c = t % 12;
      *(uint4*)&K_l[r][c * 8] = *(const uint4*)&Kbase[(size_t)(seg0 + kt + r) * HDP + c * 8];
    }
    for (int t = tid; t < 80 * 8; t += 256) {
      int r = t / 8, c = t % 8;
      *(uint4*)&V_l[r][c * 8] = *(const uint4*)&Vbase[(size_t)r * SEQ + seg0 + kt + c * 8];
    }
    __syncthreads();

    // S = Q K^T (16 q x 64 k), online softmax
    f32x4 S[4];
    #pragma unroll
    for (int ct = 0; ct < 4; ++ct) {
      S[ct] = z4;
      #pragma unroll
      for (int kc = 0; kc < 3; ++kc) {
        f16x8 kF = *(const f16x8*)&K_l[ct * 16 + lr][kc * 32 + quad * 8];
        S[ct] = __builtin_amdgcn_mfma_f32_16x16x32_f16(qF[kc], kF, S[ct], 0, 0, 0);
      }
    }
    f32x4 mx = S[0];
    #pragma unroll
    for (int ct = 1; ct < 4; ++ct) {
      mx.x = fmaxf(mx.x, S[ct].x); mx.y = fmaxf(mx.y, S[ct].y);
      mx.z = fmaxf(mx.z, S[ct].z); mx.w = fmaxf(mx.w, S[ct].w);
    }
    #pragma unroll
    for (int off = 1; off < 16; off <<= 1) {
      mx.x = fmaxf(mx.x, __shfl_xor(mx.x, off, 64));
      mx.y = fmaxf(mx.y, __shfl_xor(mx.y, off, 64));
      mx.z = fmaxf(mx.z, __shfl_xor(mx.z, off, 64));
      mx.w = fmaxf(mx.w, __shfl_xor(mx.w, off, 64));
    }
    f32x4 mnew;
    mnew.x = fmaxf(mrow.x, mx.x); mnew.y = fmaxf(mrow.y, mx.y);
    mnew.z = fmaxf(mrow.z, mx.z); mnew.w = fmaxf(mrow.w, mx.w);
    f32x4 alpha = exp4(mrow - mnew);
    mrow = mnew;
    f32x4 rs = z4;
    #pragma unroll
    for (int ct = 0; ct < 4; ++ct) {
      S[ct] = exp4(S[ct] - mnew);
      rs += S[ct];
    }
    #pragma unroll
    for (int off = 1; off < 16; off <<= 1) {
      rs.x += __shfl_xor(rs.x, off, 64);
      rs.y += __shfl_xor(rs.y, off, 64);
      rs.z += __shfl_xor(rs.z, off, 64);
      rs.w += __shfl_xor(rs.w, off, 64);
    }
    lrow = lrow * alpha + rs;
    #pragma unroll
    for (int n = 0; n < 5; ++n) Oacc[n] *= alpha;
    // P to LDS (C layout: row=quad*4+r, col=ct*16+lr), wave-private
    #pragma unroll
    for (int ct = 0; ct < 4; ++ct) {
      P_l[w][quad * 4 + 0][ct * 16 + lr] = f2h(S[ct].x);
      P_l[w][quad * 4 + 1][ct * 16 + lr] = f2h(S[ct].y);
      P_l[w][quad * 4 + 2][ct * 16 + lr] = f2h(S[ct].z);
      P_l[w][quad * 4 + 3][ct * 16 + lr] = f2h(S[ct].w);
    }

    // PV: O += P V  (fragments hoisted: each V_l row read once)
    #pragma unroll
    for (int kc2 = 0; kc2 < 2; ++kc2) {
      f16x8 pF = *(const f16x8*)&P_l[w][lr][kc2 * 32 + quad * 8];
      #pragma unroll
      for (int n = 0; n < 5; ++n) {
        f16x8 vF = *(const f16x8*)&V_l[n * 16 + lr][kc2 * 32 + quad * 8];
        Oacc[n] = __builtin_amdgcn_mfma_f32_16x16x32_f16(pF, vF, Oacc[n], 0, 0, 0);
      }
    }
    __syncthreads();
  }

  // epilogue: normalize by 1/l, store fp16
  f32x4 inv;
  inv.x = 1.0f / lrow.x; inv.y = 1.0f / lrow.y;
  inv.z = 1.0f / lrow.z; inv.w = 1.0f / lrow.w;
  #pragma unroll
  for (int n = 0; n < 5; ++n) {
    int rowb = q0b + w * 16 + quad * 4;
    int col = h * HD + n * 16 + lr;
    attnO[(size_t)(rowb + 0) * EMB + col] = f2h(Oacc[n].x * inv.x);
    attnO[(size_t)(rowb + 1) * EMB + col] = f2h(Oacc[n].y * inv.y);
    attnO[(size_t)(rowb + 2) * EMB + col] = f2h(Oacc[n].z * inv.z);
    attnO[(size_t)(rowb + 3) * EMB + col] = f2h(Oacc[n].w * inv.w);
  }
}

extern "C" void kernel_launch(void* const* d_in, const int* in_sizes, int n_in,
                              void* d_out, int out_size, void* d_ws, size_t ws_size,
                              hipStream_t stream) {
  const float* hs     = (const float*)d_in[0];
  const float* w_qkv  = (const float*)d_in[1];
  const float* b_qkv  = (const float*)d_in[2];
  const float* w_proj = (const float*)d_in[3];
  const float* b_proj = (const float*)d_in[4];
  const float* cosp   = (const float*)d_in[5];
  const float* sinp   = (const float*)d_in[6];
  float* out = (float*)d_out;

  char* p = (char*)d_ws;
  auto take = [&](size_t bytes) { char* q = p; p += (bytes + 255) & ~(size_t)255; return q; };
  u16* hsH    = (u16*)take((size_t)SEQ * EMB * 2);
  u16* wqkvH  = (u16*)take((size_t)O3 * EMB * 2);
  u16* wprojH = (u16*)take((size_t)EMB * EMB * 2);
  u16* qkvO   = (u16*)take((size_t)SEQ * O3 * 2);
  u16* Qp     = (u16*)take((size_t)NH * SEQ * HDP * 2);
  u16* Kp     = (u16*)take((size_t)NH * SEQ * HDP * 2);
  u16* Vt     = (u16*)take((size_t)NH * HD * SEQ * 2);
  u16* attnH  = (u16*)take((size_t)SEQ * EMB * 2);

  int n1 = SEQ * EMB / 4, n2 = O3 * EMB / 4, n3 = EMB * EMB / 4;
  cvt4_kernel<<<(n1 + 255) / 256, 256, 0, stream>>>(hs, hsH, n1);
  cvt4_kernel<<<(n2 + 255) / 256, 256, 0, stream>>>(w_qkv, wqkvH, n2);
  cvt4_kernel<<<(n3 + 255) / 256, 256, 0, stream>>>(w_proj, wprojH, n3);

  gemm_bias_kernel<0><<<dim3(O3 / 128, SEQ / 128), 256, 0, stream>>>(hsH, wqkvH, b_qkv, qkvO, O3, EMB);

  rope_reorg_kernel<<<dim3(SEQ / 64, NH), 256, 0, stream>>>(qkvO, cosp, sinp, Qp, Kp, Vt);

  attn_kernel<<<dim3(SEGLEN / 64, NH, NSEG), 256, 0, stream>>>(Qp, Kp, Vt, attnH);

  gemm_bias_kernel<1><<<dim3(EMB / 128, SEQ / 128), 256, 0, stream>>>(attnH, wprojH, b_proj, out, EMB, EMB);
}

// Round 5
// 301.078 us; speedup vs baseline: 1.5145x; 1.0425x over previous
//
#include <hip/hip_runtime.h>

#define SEQ   4096
#define EMB   1280
#define NH    16
#define HD    80
#define HDP   96
#define O3    3840
#define SEGLEN 1024
#define NSEG  4
#define SCALE 8.94427190999915878564f  // sqrt(80); reference MULTIPLIES scores by sqrt(d)

typedef unsigned short u16;
typedef __attribute__((ext_vector_type(8))) _Float16 f16x8;
typedef __attribute__((ext_vector_type(4))) _Float16 f16x4;
typedef __attribute__((ext_vector_type(4))) float    f32x4;

__device__ __forceinline__ u16 f2h(float f) {
  union { _Float16 h; u16 u; } v; v.h = (_Float16)f; return v.u;
}
__device__ __forceinline__ float h2f(u16 b) {
  union { u16 u; _Float16 h; } v; v.u = b; return (float)v.h;
}
__device__ __forceinline__ f32x4 exp4(f32x4 x) {
  f32x4 r; r.x = __expf(x.x); r.y = __expf(x.y); r.z = __expf(x.z); r.w = __expf(x.w); return r;
}
// async global->LDS, 16B per lane. LDS dest must be wave-uniform base + lane*16.
__device__ __forceinline__ void gl2lds16(const u16* g, u16* l) {
  __builtin_amdgcn_global_load_lds(
      (const __attribute__((address_space(1))) unsigned int*)g,
      (__attribute__((address_space(3))) unsigned int*)l, 16, 0, 0);
}

// ---------------- fp32 -> fp16 convert (x4 vectorized) ----------------
__global__ void cvt4_kernel(const float* __restrict__ in, u16* __restrict__ out, int n4) {
  int i = blockIdx.x * blockDim.x + threadIdx.x;
  if (i >= n4) return;
  float4 f = ((const float4*)in)[i];
  union { u16 h[4]; uint2 v; } o;
  o.h[0] = f2h(f.x); o.h[1] = f2h(f.y); o.h[2] = f2h(f.z); o.h[3] = f2h(f.w);
  ((uint2*)out)[i] = o.v;
}

// ---------------- fp16 MFMA GEMM: C[M][N] = A[M][K] * W[N][K]^T + bias ----------------
// m97 pattern: global_load_lds width=16, unpadded [128][32] LDS (lane-contiguous dest).
template<int OUTF>
__global__ __launch_bounds__(256)
void gemm_bias_kernel(const u16* __restrict__ A, const u16* __restrict__ W,
                      const float* __restrict__ bias, void* __restrict__ Cout,
                      int N, int K) {
  __shared__ u16 As[128][32];
  __shared__ u16 Bs[128][32];
  const int tid  = threadIdx.x;
  const int bm   = blockIdx.y, bn = blockIdx.x;
  const int lane = tid & 63;
  const int wid  = tid >> 6;
  const int wm   = (wid >> 1) * 64, wn = (wid & 1) * 64;
  const int lr   = lane & 15, quad = lane >> 4;

  f32x4 acc[4][4];
  const f32x4 z4 = {0.f, 0.f, 0.f, 0.f};
  #pragma unroll
  for (int i = 0; i < 4; ++i)
    #pragma unroll
    for (int j = 0; j < 4; ++j) acc[i][j] = z4;

  const int grow = tid >> 2;        // 0..63
  const int gcol = (tid & 3) * 8;   // 0,8,16,24
  const u16* Ab = A + (size_t)(bm * 128) * K;
  const u16* Wb = W + (size_t)(bn * 128) * K;
  u16* AsL = &As[0][0] + tid * 8;   // = tid*16 bytes: row tid>>2, col (tid&3)*8
  u16* BsL = &Bs[0][0] + tid * 8;

  for (int kt = 0; kt < K; kt += 32) {
    gl2lds16(&Ab[(size_t)grow * K + kt + gcol],        AsL);
    gl2lds16(&Ab[(size_t)(grow + 64) * K + kt + gcol], AsL + 64 * 32);
    gl2lds16(&Wb[(size_t)grow * K + kt + gcol],        BsL);
    gl2lds16(&Wb[(size_t)(grow + 64) * K + kt + gcol], BsL + 64 * 32);
    __syncthreads();
    f16x8 aF[4], bF[4];
    #pragma unroll
    for (int i = 0; i < 4; ++i) aF[i] = *(const f16x8*)&As[wm + i * 16 + lr][quad * 8];
    #pragma unroll
    for (int j = 0; j < 4; ++j) bF[j] = *(const f16x8*)&Bs[wn + j * 16 + lr][quad * 8];
    #pragma unroll
    for (int i = 0; i < 4; ++i)
      #pragma unroll
      for (int j = 0; j < 4; ++j)
        acc[i][j] = __builtin_amdgcn_mfma_f32_16x16x32_f16(aF[i], bF[j], acc[i][j], 0, 0, 0);
    __syncthreads();
  }

  // epilogue: D row = quad*4 + r, col = lr
  #pragma unroll
  for (int i = 0; i < 4; ++i) {
    int rowb = bm * 128 + wm + i * 16 + quad * 4;
    #pragma unroll
    for (int j = 0; j < 4; ++j) {
      int col = bn * 128 + wn + j * 16 + lr;
      float bv = bias[col];
      #pragma unroll
      for (int r = 0; r < 4; ++r) {
        float v = acc[i][j][r] + bv;
        if (OUTF) ((float*)Cout)[(size_t)(rowb + r) * N + col] = v;
        else      ((u16*)Cout)[(size_t)(rowb + r) * N + col] = f2h(v);
      }
    }
  }
}

// ---------------- RoPE + layout reorg (coalesced Vt via LDS transpose) ----------------
// block = (64 s-rows, 1 head). qkv[s][3840] -> Qp[h][s][96] (*SCALE), Kp[h][s][96], Vt[h][d][s]
__global__ __launch_bounds__(256)
void rope_reorg_kernel(const u16* __restrict__ qkv, const float* __restrict__ cosp,
                       const float* __restrict__ sinp, u16* __restrict__ Qp,
                       u16* __restrict__ Kp, u16* __restrict__ Vt) {
  __shared__ u16 Vs[64][90];   // 64 s x 80 d, stride 90
  const int tid = threadIdx.x;
  const int s0 = blockIdx.x * 64;
  const int h  = blockIdx.y;

  // phase A: Q/K rope, coalesced read+write (d innermost)
  for (int i = tid; i < 64 * HDP; i += 256) {
    int r = i / HDP, d = i % HDP;
    int s = s0 + r;
    size_t po = ((size_t)h * SEQ + s) * HDP + d;
    if (d >= HD) { Qp[po] = 0; Kp[po] = 0; continue; }
    const size_t rowb = (size_t)s * O3;
    float q = h2f(qkv[rowb + h * HD + d]);
    float k = h2f(qkv[rowb + EMB + h * HD + d]);
    float c  = cosp[s * HD + d];
    float sn = sinp[s * HD + d];
    int   dp = (d < 40) ? d + 40 : d - 40;
    float qp_ = h2f(qkv[rowb + h * HD + dp]);
    float kp_ = h2f(qkv[rowb + EMB + h * HD + dp]);
    float qo = (d < 40) ? (q * c - qp_ * sn) : (q * c + qp_ * sn);
    float ko = (d < 40) ? (k * c - kp_ * sn) : (k * c + kp_ * sn);
    Qp[po] = f2h(qo * SCALE);
    Kp[po] = f2h(ko);
  }

  // phase B: V transpose through LDS
  for (int i = tid; i < 64 * HD; i += 256) {
    int r = i / HD, c = i % HD;
    Vs[r][c] = qkv[(size_t)(s0 + r) * O3 + 2 * EMB + h * HD + c];
  }
  __syncthreads();
  for (int i = tid; i < HD * 64; i += 256) {
    int d = i / 64, s = i % 64;
    Vt[((size_t)(h * HD + d)) * SEQ + s0 + s] = Vs[s][d];
  }
}

// ---------------- flash attention, swapped-QK: block = 64 q x (head, seg), 4 waves x 16 q ----------
// S^T = K Q^T via mfma(A=K, B=Q): lane holds scores for q = lr at c = ct*16 + quad*4 + r.
// Softmax reduction = 2 scalar shuffles. P feeds v_mfma_f32_16x16x16f16 A-operand DIRECTLY
// (k = quad*4+j matches c = quad*4+r) -- no LDS round-trip for P.
__global__ __launch_bounds__(256)
void attn_kernel(const u16* __restrict__ Qp, const u16* __restrict__ Kp,
                 const u16* __restrict__ Vt, u16* __restrict__ attnO) {
  __shared__ u16 K_l[64][104];     // 64 k-rows x 96 dims (+8 pad) = 13.3 KB
  __shared__ u16 V_l[80][72];      // 80 dims x 64 k-cols (+8 pad) = 11.5 KB

  const int tid = threadIdx.x;
  const int lane = tid & 63, w = tid >> 6;
  const int lr = lane & 15, quad = lane >> 4;
  const int h = blockIdx.y, sg = blockIdx.z;
  const int seg0 = sg * SEGLEN;
  const int q0b = seg0 + blockIdx.x * 64;

  // Q B-fragments: B[n=q][k=d], lane lr -> Q[q0b + w*16 + lr][kc*32 + quad*8 + j]
  f16x8 qF[3];
  {
    int qrow = q0b + w * 16 + lr;
    #pragma unroll
    for (int kc = 0; kc < 3; ++kc)
      qF[kc] = *(const f16x8*)&Qp[((size_t)h * SEQ + qrow) * HDP + kc * 32 + quad * 8];
  }

  const u16* Kbase = Kp + (size_t)h * SEQ * HDP;
  const u16* Vbase = Vt + (size_t)h * HD * SEQ;

  const f32x4 z4 = {0.f, 0.f, 0.f, 0.f};
  float m_r = -3.0e38f;   // running max for q = lr (replicated across quads)
  float l_r = 0.0f;       // running denom for q = lr
  f32x4 Oacc[5];          // Oacc[n5][r] = O[q = quad*4+r][d = n5*16+lr]
  #pragma unroll
  for (int n = 0; n < 5; ++n) Oacc[n] = z4;

  for (int kt = 0; kt < SEGLEN; kt += 64) {
    // stage K chunk (64 x 96) and V chunk (80 x 64)
    for (int t = tid; t < 64 * 12; t += 256) {
      int r = t / 12, c = t % 12;
      *(uint4*)&K_l[r][c * 8] = *(const uint4*)&Kbase[(size_t)(seg0 + kt + r) * HDP + c * 8];
    }
    for (int t = tid; t < 80 * 8; t += 256) {
      int r = t / 8, c = t % 8;
      *(uint4*)&V_l[r][c * 8] = *(const uint4*)&Vbase[(size_t)r * SEQ + seg0 + kt + c * 8];
    }
    __syncthreads();

    // S^T = K Q^T: S[ct][r] = score(q=lr, c = kt + ct*16 + quad*4 + r)
    f32x4 S[4];
    #pragma unroll
    for (int ct = 0; ct < 4; ++ct) {
      S[ct] = z4;
      #pragma unroll
      for (int kc = 0; kc < 3; ++kc) {
        f16x8 kF = *(const f16x8*)&K_l[ct * 16 + lr][kc * 32 + quad * 8];
        S[ct] = __builtin_amdgcn_mfma_f32_16x16x32_f16(kF, qF[kc], S[ct], 0, 0, 0);
      }
    }

    // online softmax for q = lr: reduce over 16 regs + 2 shuffles (quad dimension)
    float mx = fmaxf(fmaxf(S[0].x, S[0].y), fmaxf(S[0].z, S[0].w));
    #pragma unroll
    for (int ct = 1; ct < 4; ++ct)
      mx = fmaxf(mx, fmaxf(fmaxf(S[ct].x, S[ct].y), fmaxf(S[ct].z, S[ct].w)));
    mx = fmaxf(mx, __shfl_xor(mx, 16, 64));
    mx = fmaxf(mx, __shfl_xor(mx, 32, 64));
    float mnew = fmaxf(m_r, mx);
    float alpha = __expf(m_r - mnew);
    m_r = mnew;

    f32x4 mv = {mnew, mnew, mnew, mnew};
    float rs = 0.f;
    #pragma unroll
    for (int ct = 0; ct < 4; ++ct) {
      S[ct] = exp4(S[ct] - mv);
      rs += S[ct].x + S[ct].y + S[ct].z + S[ct].w;
    }
    rs += __shfl_xor(rs, 16, 64);
    rs += __shfl_xor(rs, 32, 64);
    l_r = l_r * alpha + rs;

    // broadcast alpha into D-row layout: alpha for q = quad*4 + r lives at lane quad*4+r
    f32x4 al;
    al.x = __shfl(alpha, quad * 4 + 0, 64);
    al.y = __shfl(alpha, quad * 4 + 1, 64);
    al.z = __shfl(alpha, quad * 4 + 2, 64);
    al.w = __shfl(alpha, quad * 4 + 3, 64);
    #pragma unroll
    for (int n = 0; n < 5; ++n) Oacc[n] *= al;

    // P fragments: f16x4 per ct, DIRECT from registers (A[m=q=lr][k=quad*4+j])
    f16x4 pF[4];
    #pragma unroll
    for (int ct = 0; ct < 4; ++ct) {
      pF[ct].x = (_Float16)S[ct].x; pF[ct].y = (_Float16)S[ct].y;
      pF[ct].z = (_Float16)S[ct].z; pF[ct].w = (_Float16)S[ct].w;
    }

    // PV: O[q][d] += sum_c P[q][c] V[c][d] via 16x16x16 MFMA
    // B[n=d][k=c]: lane lr -> V[c = ct*16 + quad*4 + j][d = n5*16 + lr] = V_l[n5*16+lr][ct*16+quad*4+j]
    #pragma unroll
    for (int ct = 0; ct < 4; ++ct)
      #pragma unroll
      for (int n = 0; n < 5; ++n) {
        f16x4 vF = *(const f16x4*)&V_l[n * 16 + lr][ct * 16 + quad * 4];
        Oacc[n] = __builtin_amdgcn_mfma_f32_16x16x16f16(pF[ct], vF, Oacc[n], 0, 0, 0);
      }
    __syncthreads();
  }

  // epilogue: normalize by 1/l (broadcast into D-row layout), store fp16
  f32x4 linv;
  linv.x = 1.0f / __shfl(l_r, quad * 4 + 0, 64);
  linv.y = 1.0f / __shfl(l_r, quad * 4 + 1, 64);
  linv.z = 1.0f / __shfl(l_r, quad * 4 + 2, 64);
  linv.w = 1.0f / __shfl(l_r, quad * 4 + 3, 64);
  #pragma unroll
  for (int n = 0; n < 5; ++n) {
    int rowb = q0b + w * 16 + quad * 4;
    int col = h * HD + n * 16 + lr;
    attnO[(size_t)(rowb + 0) * EMB + col] = f2h(Oacc[n].x * linv.x);
    attnO[(size_t)(rowb + 1) * EMB + col] = f2h(Oacc[n].y * linv.y);
    attnO[(size_t)(rowb + 2) * EMB + col] = f2h(Oacc[n].z * linv.z);
    attnO[(size_t)(rowb + 3) * EMB + col] = f2h(Oacc[n].w * linv.w);
  }
}

extern "C" void kernel_launch(void* const* d_in, const int* in_sizes, int n_in,
                              void* d_out, int out_size, void* d_ws, size_t ws_size,
                              hipStream_t stream) {
  const float* hs     = (const float*)d_in[0];
  const float* w_qkv  = (const float*)d_in[1];
  const float* b_qkv  = (const float*)d_in[2];
  const float* w_proj = (const float*)d_in[3];
  const float* b_proj = (const float*)d_in[4];
  const float* cosp   = (const float*)d_in[5];
  const float* sinp   = (const float*)d_in[6];
  float* out = (float*)d_out;

  char* p = (char*)d_ws;
  auto take = [&](size_t bytes) { char* q = p; p += (bytes + 255) & ~(size_t)255; return q; };
  u16* hsH    = (u16*)take((size_t)SEQ * EMB * 2);
  u16* wqkvH  = (u16*)take((size_t)O3 * EMB * 2);
  u16* wprojH = (u16*)take((size_t)EMB * EMB * 2);
  u16* qkvO   = (u16*)take((size_t)SEQ * O3 * 2);
  u16* Qp     = (u16*)take((size_t)NH * SEQ * HDP * 2);
  u16* Kp     = (u16*)take((size_t)NH * SEQ * HDP * 2);
  u16* Vt     = (u16*)take((size_t)NH * HD * SEQ * 2);
  u16* attnH  = (u16*)take((size_t)SEQ * EMB * 2);

  int n1 = SEQ * EMB / 4, n2 = O3 * EMB / 4, n3 = EMB * EMB / 4;
  cvt4_kernel<<<(n1 + 255) / 256, 256, 0, stream>>>(hs, hsH, n1);
  cvt4_kernel<<<(n2 + 255) / 256, 256, 0, stream>>>(w_qkv, wqkvH, n2);
  cvt4_kernel<<<(n3 + 255) / 256, 256, 0, stream>>>(w_proj, wprojH, n3);

  gemm_bias_kernel<0><<<dim3(O3 / 128, SEQ / 128), 256, 0, stream>>>(hsH, wqkvH, b_qkv, qkvO, O3, EMB);

  rope_reorg_kernel<<<dim3(SEQ / 64, NH), 256, 0, stream>>>(qkvO, cosp, sinp, Qp, Kp, Vt);

  attn_kernel<<<dim3(SEGLEN / 64, NH, NSEG), 256, 0, stream>>>(Qp, Kp, Vt, attnH);

  gemm_bias_kernel<1><<<dim3(EMB / 128, SEQ / 128), 256, 0, stream>>>(attnH, wprojH, b_proj, out, EMB, EMB);
}

// Round 6
// 285.839 us; speedup vs baseline: 1.5952x; 1.0533x over previous
//
#include <hip/hip_runtime.h>

#define SEQ   4096
#define EMB   1280
#define NH    16
#define HD    80
#define HDP   96
#define O3    3840
#define SEGLEN 1024
#define NSEG  4
#define SCALE 8.94427190999915878564f  // sqrt(80); reference MULTIPLIES scores by sqrt(d)

typedef unsigned short u16;
typedef __attribute__((ext_vector_type(8))) _Float16 f16x8;
typedef __attribute__((ext_vector_type(4))) _Float16 f16x4;
typedef __attribute__((ext_vector_type(4))) float    f32x4;

__device__ __forceinline__ u16 f2h(float f) {
  union { _Float16 h; u16 u; } v; v.h = (_Float16)f; return v.u;
}
__device__ __forceinline__ float h2f(u16 b) {
  union { u16 u; _Float16 h; } v; v.u = b; return (float)v.h;
}
__device__ __forceinline__ f32x4 exp4(f32x4 x) {
  f32x4 r; r.x = __expf(x.x); r.y = __expf(x.y); r.z = __expf(x.z); r.w = __expf(x.w); return r;
}
// async global->LDS, 16B per lane. LDS dest must be wave-uniform base + lane*16.
__device__ __forceinline__ void gl2lds16(const u16* g, u16* l) {
  __builtin_amdgcn_global_load_lds(
      (const __attribute__((address_space(1))) unsigned int*)g,
      (__attribute__((address_space(3))) unsigned int*)l, 16, 0, 0);
}

// ---------------- fp32 -> fp16 convert (x4 vectorized) ----------------
__global__ void cvt4_kernel(const float* __restrict__ in, u16* __restrict__ out, int n4) {
  int i = blockIdx.x * blockDim.x + threadIdx.x;
  if (i >= n4) return;
  float4 f = ((const float4*)in)[i];
  union { u16 h[4]; uint2 v; } o;
  o.h[0] = f2h(f.x); o.h[1] = f2h(f.y); o.h[2] = f2h(f.z); o.h[3] = f2h(f.w);
  ((uint2*)out)[i] = o.v;
}

// ---------------- fp16 MFMA GEMM: C[M][N] = A[M][K] * W[N][K]^T + bias ----------------
// BK=64 (32 MFMAs per barrier) + XOR chunk swizzle:
//   stage:  lane tid -> LDS slot tid*16B = (row=tid>>3, slot=tid&7), holding GLOBAL chunk (tid&7)^(row&7)
//   read:   global chunk g of row r lives at LDS slot g^(r&7); r&7 == lr&7 for fragment rows
//   => 16 lr-lanes hit 8 distinct 16B slots -> 2-way conflict (free, m136)
template<int OUTF>
__global__ __launch_bounds__(256)
void gemm_bias_kernel(const u16* __restrict__ A, const u16* __restrict__ W,
                      const float* __restrict__ bias, void* __restrict__ Cout,
                      int N, int K) {
  __shared__ u16 As[128][64];
  __shared__ u16 Bs[128][64];
  const int tid  = threadIdx.x;
  const int bm   = blockIdx.y, bn = blockIdx.x;
  const int lane = tid & 63;
  const int wid  = tid >> 6;
  const int wm   = (wid >> 1) * 64, wn = (wid & 1) * 64;
  const int lr   = lane & 15, quad = lane >> 4;

  f32x4 acc[4][4];
  const f32x4 z4 = {0.f, 0.f, 0.f, 0.f};
  #pragma unroll
  for (int i = 0; i < 4; ++i)
    #pragma unroll
    for (int j = 0; j < 4; ++j) acc[i][j] = z4;

  const int arow = tid >> 3;                      // 0..31 (row within 32-row staging round)
  const int acol = (((tid & 7) ^ (arow & 7)) * 8); // swizzled GLOBAL col chunk
  const u16* Ab = A + (size_t)(bm * 128) * K;
  const u16* Wb = W + (size_t)(bn * 128) * K;
  u16* AsL = &As[0][0] + tid * 8;                 // dest = base + tid*16B (lane-contiguous)
  u16* BsL = &Bs[0][0] + tid * 8;

  for (int kt = 0; kt < K; kt += 64) {
    #pragma unroll
    for (int r = 0; r < 4; ++r) {
      gl2lds16(&Ab[(size_t)(arow + r * 32) * K + kt + acol], AsL + r * 2048);
      gl2lds16(&Wb[(size_t)(arow + r * 32) * K + kt + acol], BsL + r * 2048);
    }
    __syncthreads();
    #pragma unroll
    for (int k32 = 0; k32 < 2; ++k32) {
      const int c = (((k32 * 4 + quad) ^ (lr & 7)) * 8);
      f16x8 aF[4], bF[4];
      #pragma unroll
      for (int i = 0; i < 4; ++i) {
        aF[i] = *(const f16x8*)&As[wm + i * 16 + lr][c];
        bF[i] = *(const f16x8*)&Bs[wn + i * 16 + lr][c];
      }
      #pragma unroll
      for (int i = 0; i < 4; ++i)
        #pragma unroll
        for (int j = 0; j < 4; ++j)
          acc[i][j] = __builtin_amdgcn_mfma_f32_16x16x32_f16(aF[i], bF[j], acc[i][j], 0, 0, 0);
    }
    __syncthreads();
  }

  // epilogue: D row = quad*4 + r, col = lr
  #pragma unroll
  for (int i = 0; i < 4; ++i) {
    int rowb = bm * 128 + wm + i * 16 + quad * 4;
    #pragma unroll
    for (int j = 0; j < 4; ++j) {
      int col = bn * 128 + wn + j * 16 + lr;
      float bv = bias[col];
      #pragma unroll
      for (int r = 0; r < 4; ++r) {
        float v = acc[i][j][r] + bv;
        if (OUTF) ((float*)Cout)[(size_t)(rowb + r) * N + col] = v;
        else      ((u16*)Cout)[(size_t)(rowb + r) * N + col] = f2h(v);
      }
    }
  }
}

// ---------------- RoPE + layout reorg (coalesced Vt via LDS transpose) ----------------
// block = (64 s-rows, 1 head). qkv[s][3840] -> Qp[h][s][96] (*SCALE), Kp[h][s][96], Vt[h][d][s]
__global__ __launch_bounds__(256)
void rope_reorg_kernel(const u16* __restrict__ qkv, const float* __restrict__ cosp,
                       const float* __restrict__ sinp, u16* __restrict__ Qp,
                       u16* __restrict__ Kp, u16* __restrict__ Vt) {
  __shared__ u16 Vs[64][90];   // 64 s x 80 d, stride 90
  const int tid = threadIdx.x;
  const int s0 = blockIdx.x * 64;
  const int h  = blockIdx.y;

  // phase A: Q/K rope, coalesced read+write (d innermost)
  for (int i = tid; i < 64 * HDP; i += 256) {
    int r = i / HDP, d = i % HDP;
    int s = s0 + r;
    size_t po = ((size_t)h * SEQ + s) * HDP + d;
    if (d >= HD) { Qp[po] = 0; Kp[po] = 0; continue; }
    const size_t rowb = (size_t)s * O3;
    float q = h2f(qkv[rowb + h * HD + d]);
    float k = h2f(qkv[rowb + EMB + h * HD + d]);
    float c  = cosp[s * HD + d];
    float sn = sinp[s * HD + d];
    int   dp = (d < 40) ? d + 40 : d - 40;
    float qp_ = h2f(qkv[rowb + h * HD + dp]);
    float kp_ = h2f(qkv[rowb + EMB + h * HD + dp]);
    float qo = (d < 40) ? (q * c - qp_ * sn) : (q * c + qp_ * sn);
    float ko = (d < 40) ? (k * c - kp_ * sn) : (k * c + kp_ * sn);
    Qp[po] = f2h(qo * SCALE);
    Kp[po] = f2h(ko);
  }

  // phase B: V transpose through LDS
  for (int i = tid; i < 64 * HD; i += 256) {
    int r = i / HD, c = i % HD;
    Vs[r][c] = qkv[(size_t)(s0 + r) * O3 + 2 * EMB + h * HD + c];
  }
  __syncthreads();
  for (int i = tid; i < HD * 64; i += 256) {
    int d = i / 64, s = i % 64;
    Vt[((size_t)(h * HD + d)) * SEQ + s0 + s] = Vs[s][d];
  }
}

// ---------------- flash attention, swapped-QK: block = 64 q x (head, seg), 4 waves x 16 q ----------
// S^T = K Q^T via mfma(A=K, B=Q): lane holds scores for q = lr at c = ct*16 + quad*4 + r.
// Softmax reduction = 2 scalar shuffles. P feeds v_mfma_f32_16x16x16f16 A-operand DIRECTLY.
__global__ __launch_bounds__(256)
void attn_kernel(const u16* __restrict__ Qp, const u16* __restrict__ Kp,
                 const u16* __restrict__ Vt, u16* __restrict__ attnO) {
  __shared__ u16 K_l[64][104];     // 64 k-rows x 96 dims (+8 pad) = 13.3 KB
  __shared__ u16 V_l[80][72];      // 80 dims x 64 k-cols (+8 pad) = 11.5 KB

  const int tid = threadIdx.x;
  const int lane = tid & 63, w = tid >> 6;
  const int lr = lane & 15, quad = lane >> 4;
  const int h = blockIdx.y, sg = blockIdx.z;
  const int seg0 = sg * SEGLEN;
  const int q0b = seg0 + blockIdx.x * 64;

  // Q B-fragments: B[n=q][k=d], lane lr -> Q[q0b + w*16 + lr][kc*32 + quad*8 + j]
  f16x8 qF[3];
  {
    int qrow = q0b + w * 16 + lr;
    #pragma unroll
    for (int kc = 0; kc < 3; ++kc)
      qF[kc] = *(const f16x8*)&Qp[((size_t)h * SEQ + qrow) * HDP + kc * 32 + quad * 8];
  }

  const u16* Kbase = Kp + (size_t)h * SEQ * HDP;
  const u16* Vbase = Vt + (size_t)h * HD * SEQ;

  const f32x4 z4 = {0.f, 0.f, 0.f, 0.f};
  float m_r = -3.0e38f;   // running max for q = lr
  float l_r = 0.0f;       // running denom for q = lr
  f32x4 Oacc[5];          // Oacc[n5][r] = O[q = quad*4+r][d = n5*16+lr]
  #pragma unroll
  for (int n = 0; n < 5; ++n) Oacc[n] = z4;

  for (int kt = 0; kt < SEGLEN; kt += 64) {
    // stage K chunk (64 x 96) and V chunk (80 x 64)
    for (int t = tid; t < 64 * 12; t += 256) {
      int r = t / 12, c = t % 12;
      *(uint4*)&K_l[r][c * 8] = *(const uint4*)&Kbase[(size_t)(seg0 + kt + r) * HDP + c * 8];
    }
    for (int t = tid; t < 80 * 8; t += 256) {
      int r = t / 8, c = t % 8;
      *(uint4*)&V_l[r][c * 8] = *(const uint4*)&Vbase[(size_t)r * SEQ + seg0 + kt + c * 8];
    }
    __syncthreads();

    // S^T = K Q^T: S[ct][r] = score(q=lr, c = kt + ct*16 + quad*4 + r)
    f32x4 S[4];
    #pragma unroll
    for (int ct = 0; ct < 4; ++ct) {
      S[ct] = z4;
      #pragma unroll
      for (int kc = 0; kc < 3; ++kc) {
        f16x8 kF = *(const f16x8*)&K_l[ct * 16 + lr][kc * 32 + quad * 8];
        S[ct] = __builtin_amdgcn_mfma_f32_16x16x32_f16(kF, qF[kc], S[ct], 0, 0, 0);
      }
    }

    // online softmax for q = lr: reduce 16 regs + 2 shuffles
    float mx = fmaxf(fmaxf(S[0].x, S[0].y), fmaxf(S[0].z, S[0].w));
    #pragma unroll
    for (int ct = 1; ct < 4; ++ct)
      mx = fmaxf(mx, fmaxf(fmaxf(S[ct].x, S[ct].y), fmaxf(S[ct].z, S[ct].w)));
    mx = fmaxf(mx, __shfl_xor(mx, 16, 64));
    mx = fmaxf(mx, __shfl_xor(mx, 32, 64));
    float mnew = fmaxf(m_r, mx);
    float alpha = __expf(m_r - mnew);
    m_r = mnew;

    f32x4 mv = {mnew, mnew, mnew, mnew};
    float rs = 0.f;
    #pragma unroll
    for (int ct = 0; ct < 4; ++ct) {
      S[ct] = exp4(S[ct] - mv);
      rs += S[ct].x + S[ct].y + S[ct].z + S[ct].w;
    }
    rs += __shfl_xor(rs, 16, 64);
    rs += __shfl_xor(rs, 32, 64);
    l_r = l_r * alpha + rs;

    // broadcast alpha into D-row layout
    f32x4 al;
    al.x = __shfl(alpha, quad * 4 + 0, 64);
    al.y = __shfl(alpha, quad * 4 + 1, 64);
    al.z = __shfl(alpha, quad * 4 + 2, 64);
    al.w = __shfl(alpha, quad * 4 + 3, 64);
    #pragma unroll
    for (int n = 0; n < 5; ++n) Oacc[n] *= al;

    // P fragments direct from registers (A[m=q=lr][k=quad*4+j])
    f16x4 pF[4];
    #pragma unroll
    for (int ct = 0; ct < 4; ++ct) {
      pF[ct].x = (_Float16)S[ct].x; pF[ct].y = (_Float16)S[ct].y;
      pF[ct].z = (_Float16)S[ct].z; pF[ct].w = (_Float16)S[ct].w;
    }

    // PV via 16x16x16 MFMA
    #pragma unroll
    for (int ct = 0; ct < 4; ++ct)
      #pragma unroll
      for (int n = 0; n < 5; ++n) {
        f16x4 vF = *(const f16x4*)&V_l[n * 16 + lr][ct * 16 + quad * 4];
        Oacc[n] = __builtin_amdgcn_mfma_f32_16x16x16f16(pF[ct], vF, Oacc[n], 0, 0, 0);
      }
    __syncthreads();
  }

  // epilogue: normalize by 1/l, store fp16
  f32x4 linv;
  linv.x = 1.0f / __shfl(l_r, quad * 4 + 0, 64);
  linv.y = 1.0f / __shfl(l_r, quad * 4 + 1, 64);
  linv.z = 1.0f / __shfl(l_r, quad * 4 + 2, 64);
  linv.w = 1.0f / __shfl(l_r, quad * 4 + 3, 64);
  #pragma unroll
  for (int n = 0; n < 5; ++n) {
    int rowb = q0b + w * 16 + quad * 4;
    int col = h * HD + n * 16 + lr;
    attnO[(size_t)(rowb + 0) * EMB + col] = f2h(Oacc[n].x * linv.x);
    attnO[(size_t)(rowb + 1) * EMB + col] = f2h(Oacc[n].y * linv.y);
    attnO[(size_t)(rowb + 2) * EMB + col] = f2h(Oacc[n].z * linv.z);
    attnO[(size_t)(rowb + 3) * EMB + col] = f2h(Oacc[n].w * linv.w);
  }
}

extern "C" void kernel_launch(void* const* d_in, const int* in_sizes, int n_in,
                              void* d_out, int out_size, void* d_ws, size_t ws_size,
                              hipStream_t stream) {
  const float* hs     = (const float*)d_in[0];
  const float* w_qkv  = (const float*)d_in[1];
  const float* b_qkv  = (const float*)d_in[2];
  const float* w_proj = (const float*)d_in[3];
  const float* b_proj = (const float*)d_in[4];
  const float* cosp   = (const float*)d_in[5];
  const float* sinp   = (const float*)d_in[6];
  float* out = (float*)d_out;

  char* p = (char*)d_ws;
  auto take = [&](size_t bytes) { char* q = p; p += (bytes + 255) & ~(size_t)255; return q; };
  u16* hsH    = (u16*)take((size_t)SEQ * EMB * 2);
  u16* wqkvH  = (u16*)take((size_t)O3 * EMB * 2);
  u16* wprojH = (u16*)take((size_t)EMB * EMB * 2);
  u16* qkvO   = (u16*)take((size_t)SEQ * O3 * 2);
  u16* Qp     = (u16*)take((size_t)NH * SEQ * HDP * 2);
  u16* Kp     = (u16*)take((size_t)NH * SEQ * HDP * 2);
  u16* Vt     = (u16*)take((size_t)NH * HD * SEQ * 2);
  u16* attnH  = (u16*)take((size_t)SEQ * EMB * 2);

  int n1 = SEQ * EMB / 4, n2 = O3 * EMB / 4, n3 = EMB * EMB / 4;
  cvt4_kernel<<<(n1 + 255) / 256, 256, 0, stream>>>(hs, hsH, n1);
  cvt4_kernel<<<(n2 + 255) / 256, 256, 0, stream>>>(w_qkv, wqkvH, n2);
  cvt4_kernel<<<(n3 + 255) / 256, 256, 0, stream>>>(w_proj, wprojH, n3);

  gemm_bias_kernel<0><<<dim3(O3 / 128, SEQ / 128), 256, 0, stream>>>(hsH, wqkvH, b_qkv, qkvO, O3, EMB);

  rope_reorg_kernel<<<dim3(SEQ / 64, NH), 256, 0, stream>>>(qkvO, cosp, sinp, Qp, Kp, Vt);

  attn_kernel<<<dim3(SEGLEN / 64, NH, NSEG), 256, 0, stream>>>(Qp, Kp, Vt, attnH);

  gemm_bias_kernel<1><<<dim3(EMB / 128, SEQ / 128), 256, 0, stream>>>(attnH, wprojH, b_proj, out, EMB, EMB);
}

// Round 9
// 253.177 us; speedup vs baseline: 1.8010x; 1.1290x over previous
//
#include <hip/hip_runtime.h>

#define SEQ   4096
#define EMB   1280
#define NH    16
#define HD    80
#define HDP   96
#define O3    3840
#define SEGLEN 1024
#define NSEG  4
// sqrt(80) * log2(e): scores computed in log2 domain -> softmax uses native v_exp_f32 (exp2)
#define QSCALE (8.94427190999915878564f * 1.44269504088896340736f)

typedef unsigned short u16;
typedef __attribute__((ext_vector_type(8))) _Float16 f16x8;
typedef __attribute__((ext_vector_type(4))) _Float16 f16x4;
typedef __attribute__((ext_vector_type(2))) __fp16   h16x2;
typedef __attribute__((ext_vector_type(4))) float    f32x4;

__device__ __forceinline__ float ex2(float x) { return __builtin_amdgcn_exp2f(x); }

__device__ __forceinline__ u16 f2h(float f) {
  union { _Float16 h; u16 u; } v; v.h = (_Float16)f; return v.u;
}
__device__ __forceinline__ float h2f(u16 b) {
  union { u16 u; _Float16 h; } v; v.u = b; return (float)v.h;
}
__device__ __forceinline__ f32x4 exp2_4(f32x4 x) {
  f32x4 r; r.x = ex2(x.x); r.y = ex2(x.y); r.z = ex2(x.z); r.w = ex2(x.w); return r;
}
__device__ __forceinline__ f16x4 pk4(f32x4 s) {
  union { h16x2 h[2]; f16x4 f; } u;
  u.h[0] = __builtin_amdgcn_cvt_pkrtz(s.x, s.y);
  u.h[1] = __builtin_amdgcn_cvt_pkrtz(s.z, s.w);
  return u.f;
}
// async global->LDS, 16B per lane. LDS dest must be wave-uniform base + lane*16.
__device__ __forceinline__ void gl2lds16(const u16* g, u16* l) {
  __builtin_amdgcn_global_load_lds(
      (const __attribute__((address_space(1))) unsigned int*)g,
      (__attribute__((address_space(3))) unsigned int*)l, 16, 0, 0);
}

// ---------------- fused fp32 -> fp16 convert for hs, w_qkv, w_proj ----------------
#define CVT_N1 (SEQ * EMB / 4)
#define CVT_N2 (O3 * EMB / 4)
#define CVT_N3 (EMB * EMB / 4)
__global__ void cvt_all_kernel(const float* __restrict__ a, const float* __restrict__ b,
                               const float* __restrict__ c, u16* __restrict__ oa,
                               u16* __restrict__ ob, u16* __restrict__ oc) {
  int i = blockIdx.x * blockDim.x + threadIdx.x;
  const float* src; u16* dst; int j = i;
  if (j < CVT_N1)                { src = a; dst = oa; }
  else if (j < CVT_N1 + CVT_N2)  { src = b; dst = ob; j -= CVT_N1; }
  else                           { src = c; dst = oc; j -= CVT_N1 + CVT_N2; }
  float4 f = ((const float4*)src)[j];
  union { u16 h[4]; uint2 v; } o;
  o.h[0] = f2h(f.x); o.h[1] = f2h(f.y); o.h[2] = f2h(f.z); o.h[3] = f2h(f.w);
  ((uint2*)dst)[j] = o.v;
}

// ---------------- fp16 MFMA GEMM: C[M][N] = A[M][K] * W[N][K]^T + bias ----------------
// BK=64 (32 MFMAs per barrier) + XOR chunk swizzle (conflict-free, verified R6: 0 conflicts)
template<int OUTF>
__global__ __launch_bounds__(256)
void gemm_bias_kernel(const u16* __restrict__ A, const u16* __restrict__ W,
                      const float* __restrict__ bias, void* __restrict__ Cout,
                      int N, int K) {
  __shared__ u16 As[128][64];
  __shared__ u16 Bs[128][64];
  const int tid  = threadIdx.x;
  const int bm   = blockIdx.y, bn = blockIdx.x;
  const int lane = tid & 63;
  const int wid  = tid >> 6;
  const int wm   = (wid >> 1) * 64, wn = (wid & 1) * 64;
  const int lr   = lane & 15, quad = lane >> 4;

  f32x4 acc[4][4];
  const f32x4 z4 = {0.f, 0.f, 0.f, 0.f};
  #pragma unroll
  for (int i = 0; i < 4; ++i)
    #pragma unroll
    for (int j = 0; j < 4; ++j) acc[i][j] = z4;

  const int arow = tid >> 3;                       // 0..31
  const int acol = (((tid & 7) ^ (arow & 7)) * 8); // swizzled GLOBAL col chunk
  const u16* Ab = A + (size_t)(bm * 128) * K;
  const u16* Wb = W + (size_t)(bn * 128) * K;
  u16* AsL = &As[0][0] + tid * 8;
  u16* BsL = &Bs[0][0] + tid * 8;

  for (int kt = 0; kt < K; kt += 64) {
    #pragma unroll
    for (int r = 0; r < 4; ++r) {
      gl2lds16(&Ab[(size_t)(arow + r * 32) * K + kt + acol], AsL + r * 2048);
      gl2lds16(&Wb[(size_t)(arow + r * 32) * K + kt + acol], BsL + r * 2048);
    }
    __syncthreads();
    #pragma unroll
    for (int k32 = 0; k32 < 2; ++k32) {
      const int c = (((k32 * 4 + quad) ^ (lr & 7)) * 8);
      f16x8 aF[4], bF[4];
      #pragma unroll
      for (int i = 0; i < 4; ++i) {
        aF[i] = *(const f16x8*)&As[wm + i * 16 + lr][c];
        bF[i] = *(const f16x8*)&Bs[wn + i * 16 + lr][c];
      }
      #pragma unroll
      for (int i = 0; i < 4; ++i)
        #pragma unroll
        for (int j = 0; j < 4; ++j)
          acc[i][j] = __builtin_amdgcn_mfma_f32_16x16x32_f16(aF[i], bF[j], acc[i][j], 0, 0, 0);
    }
    __syncthreads();
  }

  #pragma unroll
  for (int i = 0; i < 4; ++i) {
    int rowb = bm * 128 + wm + i * 16 + quad * 4;
    #pragma unroll
    for (int j = 0; j < 4; ++j) {
      int col = bn * 128 + wn + j * 16 + lr;
      float bv = bias[col];
      #pragma unroll
      for (int r = 0; r < 4; ++r) {
        float v = acc[i][j][r] + bv;
        if (OUTF) ((float*)Cout)[(size_t)(rowb + r) * N + col] = v;
        else      ((u16*)Cout)[(size_t)(rowb + r) * N + col] = f2h(v);
      }
    }
  }
}

// ---------------- RoPE + layout reorg (fully vectorized IO via LDS) ----------------
// block = (64 s-rows, 1 head). qkv[s][3840] -> Qp[h][s][96] (*QSCALE), Kp[h][s][96], Vt[h][d][s]
__global__ __launch_bounds__(256)
void rope_reorg_kernel(const u16* __restrict__ qkv, const float* __restrict__ cosp,
                       const float* __restrict__ sinp, u16* __restrict__ Qp,
                       u16* __restrict__ Kp, u16* __restrict__ Vt) {
  __shared__ u16 Qs[64][80];
  __shared__ u16 Ks[64][80];
  __shared__ u16 Vs[64][88];   // stride 88: rows 16B aligned; col reads conflict-light
  const int tid = threadIdx.x;
  const int s0 = blockIdx.x * 64;
  const int h  = blockIdx.y;

  // load: 64 rows x 80 u16 x 3 arrays, uint4 vectorized
  for (int t = tid; t < 640; t += 256) {
    int r = t / 10, c = (t % 10) * 8;
    size_t g = (size_t)(s0 + r) * O3 + h * HD + c;
    *(uint4*)&Qs[r][c] = *(const uint4*)&qkv[g];
    *(uint4*)&Ks[r][c] = *(const uint4*)&qkv[g + EMB];
    *(uint4*)&Vs[r][c] = *(const uint4*)&qkv[g + 2 * EMB];
  }
  __syncthreads();

  // phase A: rope, 4 outputs per slot, uint2 writes
  for (int t = tid; t < 64 * 24; t += 256) {
    int r = t / 24, d4 = (t % 24) * 4;
    int s = s0 + r;
    size_t po = ((size_t)h * SEQ + s) * HDP + d4;
    if (d4 >= HD) {
      uint2 z = make_uint2(0, 0);
      *(uint2*)&Qp[po] = z; *(uint2*)&Kp[po] = z;
      continue;
    }
    float4 cv = *(const float4*)&cosp[(size_t)s * HD + d4];
    float4 sv = *(const float4*)&sinp[(size_t)s * HD + d4];
    int dp4 = (d4 < 40) ? d4 + 40 : d4 - 40;
    float sgn = (d4 < 40) ? -1.f : 1.f;
    union { u16 h[4]; uint2 v; } oq, ok;
    const float* cp = (const float*)&cv;
    const float* sp = (const float*)&sv;
    #pragma unroll
    for (int j = 0; j < 4; ++j) {
      float q  = h2f(Qs[r][d4 + j]),  k  = h2f(Ks[r][d4 + j]);
      float qp = h2f(Qs[r][dp4 + j]), kp = h2f(Ks[r][dp4 + j]);
      oq.h[j] = f2h((q * cp[j] + sgn * qp * sp[j]) * QSCALE);
      ok.h[j] = f2h(k * cp[j] + sgn * kp * sp[j]);
    }
    *(uint2*)&Qp[po] = oq.v;
    *(uint2*)&Kp[po] = ok.v;
  }

  // phase B: V transpose, uint4 writes along s
  for (int t = tid; t < HD * 8; t += 256) {
    int d = t / 8, sc = (t % 8) * 8;
    union { u16 h[8]; uint4 v; } o;
    #pragma unroll
    for (int j = 0; j < 8; ++j) o.h[j] = Vs[sc + j][d];
    *(uint4*)&Vt[((size_t)(h * HD + d)) * SEQ + s0 + sc] = o.v;
  }
}

// ---------------- flash attention, swapped-QK + async staging + exp2 softmax ----------------
// block = 64 q x (head, seg), 4 waves x 16 q. S^T = K Q^T; P direct-to-MFMA from registers.
// K_l unpadded [64][96]; V_l [80][64] with 16B-chunk XOR swizzle.
__global__ __launch_bounds__(256)
void attn_kernel(const u16* __restrict__ Qp, const u16* __restrict__ Kp,
                 const u16* __restrict__ Vt, u16* __restrict__ attnO) {
  __shared__ u16 K_l[64][96];
  __shared__ u16 V_l[80][64];

  const int tid = threadIdx.x;
  const int lane = tid & 63, w = tid >> 6;
  const int lr = lane & 15, quad = lane >> 4;
  const int h = blockIdx.y, sg = blockIdx.z;
  const int seg0 = sg * SEGLEN;
  const int q0b = seg0 + blockIdx.x * 64;

  // Q B-fragments (q already scaled by sqrt(80)*log2e at rope time)
  f16x8 qF[3];
  {
    int qrow = q0b + w * 16 + lr;
    #pragma unroll
    for (int kc = 0; kc < 3; ++kc)
      qF[kc] = *(const f16x8*)&Qp[((size_t)h * SEQ + qrow) * HDP + kc * 32 + quad * 8];
  }

  // staging pointers: K 3 full rounds (64*12=768 slots), V 2.5 rounds (80*8=640 slots)
  const u16* Kbase = Kp + ((size_t)h * SEQ + seg0) * HDP;
  const u16* Vbase = Vt + (size_t)h * HD * SEQ + seg0;
  const u16* pK[3]; u16* dK[3];
  const u16* pV[3]; u16* dV[3];
  #pragma unroll
  for (int t = 0; t < 3; ++t) {
    int s = t * 256 + tid;
    int r = s / 12, c = s % 12;
    pK[t] = Kbase + (size_t)r * HDP + c * 8;
    dK[t] = &K_l[0][0] + s * 8;
    int rv = s / 8, cv = s % 8;
    int cg = cv ^ (rv & 7);                    // XOR chunk swizzle
    pV[t] = Vbase + (size_t)rv * SEQ + cg * 8;
    dV[t] = &V_l[0][0] + s * 8;
  }

  const f32x4 z4 = {0.f, 0.f, 0.f, 0.f};
  float m_r = -3.0e38f;
  float l_r = 0.0f;
  f32x4 Oacc[5];
  #pragma unroll
  for (int n = 0; n < 5; ++n) Oacc[n] = z4;

  for (int kt = 0; kt < SEGLEN; kt += 64) {
    gl2lds16(pK[0], dK[0]); gl2lds16(pK[1], dK[1]); gl2lds16(pK[2], dK[2]);
    gl2lds16(pV[0], dV[0]); gl2lds16(pV[1], dV[1]);
    if (tid < 128) gl2lds16(pV[2], dV[2]);
    #pragma unroll
    for (int t = 0; t < 3; ++t) { pK[t] += 64 * HDP; pV[t] += 64; }
    __syncthreads();

    // S^T = K Q^T: lane holds scores for q=lr at c = ct*16 + quad*4 + r (log2 domain)
    f32x4 S[4];
    #pragma unroll
    for (int ct = 0; ct < 4; ++ct) {
      S[ct] = z4;
      #pragma unroll
      for (int kc = 0; kc < 3; ++kc) {
        f16x8 kF = *(const f16x8*)&K_l[ct * 16 + lr][kc * 32 + quad * 8];
        S[ct] = __builtin_amdgcn_mfma_f32_16x16x32_f16(kF, qF[kc], S[ct], 0, 0, 0);
      }
    }

    // online softmax (exp2 domain), reduce 16 regs + 2 shuffles
    float mx = fmaxf(fmaxf(S[0].x, S[0].y), fmaxf(S[0].z, S[0].w));
    #pragma unroll
    for (int ct = 1; ct < 4; ++ct)
      mx = fmaxf(mx, fmaxf(fmaxf(S[ct].x, S[ct].y), fmaxf(S[ct].z, S[ct].w)));
    mx = fmaxf(mx, __shfl_xor(mx, 16, 64));
    mx = fmaxf(mx, __shfl_xor(mx, 32, 64));
    float mnew = fmaxf(m_r, mx);
    float alpha = ex2(m_r - mnew);
    m_r = mnew;

    f32x4 mv = {mnew, mnew, mnew, mnew};
    float rs = 0.f;
    #pragma unroll
    for (int ct = 0; ct < 4; ++ct) {
      S[ct] = exp2_4(S[ct] - mv);
      rs += (S[ct].x + S[ct].y) + (S[ct].z + S[ct].w);
    }
    rs += __shfl_xor(rs, 16, 64);
    rs += __shfl_xor(rs, 32, 64);
    l_r = l_r * alpha + rs;

    // rescale history only when some lane's max moved (wave-uniform skip)
    if (__ballot(alpha != 1.0f)) {
      f32x4 al;
      al.x = __shfl(alpha, quad * 4 + 0, 64);
      al.y = __shfl(alpha, quad * 4 + 1, 64);
      al.z = __shfl(alpha, quad * 4 + 2, 64);
      al.w = __shfl(alpha, quad * 4 + 3, 64);
      #pragma unroll
      for (int n = 0; n < 5; ++n) Oacc[n] *= al;
    }

    // P fragments via packed cvt, direct A-operand of 16x16x16 (k=quad*4+j == c=quad*4+r)
    f16x4 pF[4];
    #pragma unroll
    for (int ct = 0; ct < 4; ++ct) pF[ct] = pk4(S[ct]);

    // PV: vF from swizzled V_l
    #pragma unroll
    for (int ct = 0; ct < 4; ++ct) {
      const int cchunk = 2 * ct + (quad >> 1);
      #pragma unroll
      for (int n = 0; n < 5; ++n) {
        int vrow = n * 16 + lr;
        const u16* vp = &V_l[0][0] + vrow * 64 + ((cchunk ^ (vrow & 7)) << 3) + ((quad & 1) << 2);
        f16x4 vF = *(const f16x4*)vp;
        Oacc[n] = __builtin_amdgcn_mfma_f32_16x16x16f16(pF[ct], vF, Oacc[n], 0, 0, 0);
      }
    }
    __syncthreads();
  }

  // epilogue: normalize by 1/l, store fp16
  f32x4 linv;
  linv.x = 1.0f / __shfl(l_r, quad * 4 + 0, 64);
  linv.y = 1.0f / __shfl(l_r, quad * 4 + 1, 64);
  linv.z = 1.0f / __shfl(l_r, quad * 4 + 2, 64);
  linv.w = 1.0f / __shfl(l_r, quad * 4 + 3, 64);
  #pragma unroll
  for (int n = 0; n < 5; ++n) {
    int rowb = q0b + w * 16 + quad * 4;
    int col = h * HD + n * 16 + lr;
    attnO[(size_t)(rowb + 0) * EMB + col] = f2h(Oacc[n].x * linv.x);
    attnO[(size_t)(rowb + 1) * EMB + col] = f2h(Oacc[n].y * linv.y);
    attnO[(size_t)(rowb + 2) * EMB + col] = f2h(Oacc[n].z * linv.z);
    attnO[(size_t)(rowb + 3) * EMB + col] = f2h(Oacc[n].w * linv.w);
  }
}

extern "C" void kernel_launch(void* const* d_in, const int* in_sizes, int n_in,
                              void* d_out, int out_size, void* d_ws, size_t ws_size,
                              hipStream_t stream) {
  const float* hs     = (const float*)d_in[0];
  const float* w_qkv  = (const float*)d_in[1];
  const float* b_qkv  = (const float*)d_in[2];
  const float* w_proj = (const float*)d_in[3];
  const float* b_proj = (const float*)d_in[4];
  const float* cosp   = (const float*)d_in[5];
  const float* sinp   = (const float*)d_in[6];
  float* out = (float*)d_out;

  char* p = (char*)d_ws;
  auto take = [&](size_t bytes) { char* q = p; p += (bytes + 255) & ~(size_t)255; return q; };
  u16* hsH    = (u16*)take((size_t)SEQ * EMB * 2);
  u16* wqkvH  = (u16*)take((size_t)O3 * EMB * 2);
  u16* wprojH = (u16*)take((size_t)EMB * EMB * 2);
  u16* qkvO   = (u16*)take((size_t)SEQ * O3 * 2);
  u16* Qp     = (u16*)take((size_t)NH * SEQ * HDP * 2);
  u16* Kp     = (u16*)take((size_t)NH * SEQ * HDP * 2);
  u16* Vt     = (u16*)take((size_t)NH * HD * SEQ * 2);
  u16* attnH  = (u16*)take((size_t)SEQ * EMB * 2);

  int ncvt = (CVT_N1 + CVT_N2 + CVT_N3) / 256;
  cvt_all_kernel<<<ncvt, 256, 0, stream>>>(hs, w_qkv, w_proj, hsH, wqkvH, wprojH);

  gemm_bias_kernel<0><<<dim3(O3 / 128, SEQ / 128), 256, 0, stream>>>(hsH, wqkvH, b_qkv, qkvO, O3, EMB);

  rope_reorg_kernel<<<dim3(SEQ / 64, NH), 256, 0, stream>>>(qkvO, cosp, sinp, Qp, Kp, Vt);

  attn_kernel<<<dim3(SEGLEN / 64, NH, NSEG), 256, 0, stream>>>(Qp, Kp, Vt, attnH);

  gemm_bias_kernel<1><<<dim3(EMB / 128, SEQ / 128), 256, 0, stream>>>(attnH, wprojH, b_proj, out, EMB, EMB);
}